// Round 4
// baseline (538.794 us; speedup 1.0000x reference)
//
#include <hip/hip_runtime.h>
#include <math.h>

#define FS 132   // feature row stride (floats)
#define FSQ 33   // in float4
#define AS 68    // adj/score row stride
#define ASQ 17

__device__ __forceinline__ void macc(float& acc, const float4 a, const float4 b) {
  acc = fmaf(a.x, b.x, acc);
  acc = fmaf(a.y, b.y, acc);
  acc = fmaf(a.z, b.z, acc);
  acc = fmaf(a.w, b.w, acc);
}
__device__ __forceinline__ void fma4(float4& a, float s, const float4 b) {
  a.x = fmaf(s, b.x, a.x);
  a.y = fmaf(s, b.y, a.y);
  a.z = fmaf(s, b.z, a.z);
  a.w = fmaf(s, b.w, a.w);
}

// ================= K1: one block per (batch, branch): projection + GCN =================
__global__ __launch_bounds__(512, 4) void k1_branch(
    const float* __restrict__ x,
    const float* __restrict__ wq, const float* __restrict__ bq,
    const float* __restrict__ wk, const float* __restrict__ bk,
    const float* __restrict__ wv, const float* __restrict__ bv,
    const float* __restrict__ gw1, const float* __restrict__ gb1,
    const float* __restrict__ gw2, const float* __restrict__ gb2,
    float* __restrict__ F, int B)
{
  const int t = threadIdx.x;
  const int gid = blockIdx.x;
  const int br = gid / B;        // sibling blocks of a batch are B apart -> same XCD
  const int b = gid - br * B;
  const float* xb = x + (size_t)b * 8192;
  float* Fb = F + ((size_t)(br * B + b)) * 8192;

  __shared__ __align__(16) float buf[64 * FS];   // x, then f
  __shared__ __align__(16) float adjb[64 * AS];  // union: w staging (4096 <= 4352)
  __shared__ __align__(16) float gw1T[8 * FS];
  __shared__ __align__(16) float gw2s[8 * 128];
  __shared__ __align__(16) float t1T[8 * AS];
  __shared__ __align__(16) float hT[8 * AS];
  __shared__ __align__(16) float gsm[64 * 8];
  __shared__ float biasS[64], gb1s[8], gb2s[128];
  __shared__ float rinv_s[64], nrm_s[64], rinv2_s[64];

  float4* buf4 = (float4*)buf;
  float4* adj4 = (float4*)adjb;
  float4* wS4 = (float4*)adjb;  // weight staging aliases adj region

  // ---- P0: stage x, branch weight, GCN weights ----
  {
    const float4* xg = (const float4*)xb;
    for (int i = t; i < 2048; i += 512) buf4[(i >> 5) * FSQ + (i & 31)] = xg[i];
    const float* wsel = (br == 0) ? wq : (br == 1) ? wk : wv;
    const float* bsel = (br == 0) ? bq : (br == 1) ? bk : bv;
    const float4* wg = (const float4*)wsel;
    for (int i = t; i < 1024; i += 512) wS4[i] = wg[i];
    if (t < 64) biasS[t] = bsel[t];
    for (int i = t; i < 1024; i += 512) {
      gw1T[(i & 7) * FS + (i >> 3)] = gw1[i];
      gw2s[i] = gw2[i];
    }
    if (t < 8) gb1s[t] = gb1[t];
    if (t >= 8 && t < 136) gb2s[t - 8] = gb2[t - 8];
  }
  __syncthreads();

  // ---- P1: projection (4 o-rows x 1 quad per thread) + stats from registers ----
  const int o0 = (t >> 5) << 2;
  const int hq = t & 31;
  float4 a[4];
  {
#pragma unroll
    for (int i = 0; i < 4; ++i) {
      float bv0 = biasS[o0 + i];
      a[i] = make_float4(bv0, bv0, bv0, bv0);
    }
    for (int cq = 0; cq < 16; ++cq) {
      float4 x0 = buf4[(4 * cq + 0) * FSQ + hq];
      float4 x1 = buf4[(4 * cq + 1) * FSQ + hq];
      float4 x2 = buf4[(4 * cq + 2) * FSQ + hq];
      float4 x3 = buf4[(4 * cq + 3) * FSQ + hq];
#pragma unroll
      for (int i = 0; i < 4; ++i) {
        float4 w = wS4[(o0 + i) * 16 + cq];
        fma4(a[i], w.x, x0);
        fma4(a[i], w.y, x1);
        fma4(a[i], w.z, x2);
        fma4(a[i], w.w, x3);
      }
    }
    // stats: reduce over the 32 hq lanes
#pragma unroll
    for (int i = 0; i < 4; ++i) {
      float s0 = a[i].x + a[i].y + a[i].z + a[i].w;
      float s1 = a[i].x * a[i].x + a[i].y * a[i].y + a[i].z * a[i].z + a[i].w * a[i].w;
      for (int off = 16; off; off >>= 1) {
        s0 += __shfl_xor(s0, off);
        s1 += __shfl_xor(s1, off);
      }
      if ((t & 31) == 0) {
        rinv_s[o0 + i] = (s0 == 0.0f) ? 0.0f : (1.0f / s0);
        nrm_s[o0 + i] = 1.0f / fmaxf(sqrtf(s1), 1e-8f);
      }
    }
  }
  __syncthreads();  // all x reads done
#pragma unroll
  for (int i = 0; i < 4; ++i) buf4[(o0 + i) * FSQ + hq] = a[i];
  __syncthreads();

  // ---- P2: gram -> thresholded adjacency (+I); 2r x 4m tile ----
  {
    const int r0 = (t >> 4) << 1;
    const int q = t & 15;
    float acc[2][4];
#pragma unroll
    for (int i = 0; i < 2; ++i)
#pragma unroll
      for (int j = 0; j < 4; ++j) acc[i][j] = 0.0f;
    for (int hc = 0; hc < 32; ++hc) {
      float4 a0 = buf4[(r0 + 0) * FSQ + hc];
      float4 a1 = buf4[(r0 + 1) * FSQ + hc];
      float4 b0 = buf4[q * FSQ + hc];
      float4 b1 = buf4[(q + 16) * FSQ + hc];
      float4 b2 = buf4[(q + 32) * FSQ + hc];
      float4 b3 = buf4[(q + 48) * FSQ + hc];
      macc(acc[0][0], a0, b0); macc(acc[0][1], a0, b1); macc(acc[0][2], a0, b2); macc(acc[0][3], a0, b3);
      macc(acc[1][0], a1, b0); macc(acc[1][1], a1, b1); macc(acc[1][2], a1, b2); macc(acc[1][3], a1, b3);
    }
#pragma unroll
    for (int i = 0; i < 2; ++i) {
      int r = r0 + i;
      float nr = nrm_s[r];
#pragma unroll
      for (int j = 0; j < 4; ++j) {
        int m = q + 16 * j;
        float sim = acc[i][j] * nr * nrm_s[m];
        float av = (sim > 0.5f) ? 1.0f : 0.0f;
        if (r == m) av += 1.0f;
        adjb[r * AS + m] = av;
      }
    }
  }
  __syncthreads();

  // ---- P3: adj row sums (exact ints) + t1 = rownorm(f)@gw1 ----
  {
    const int n = t >> 3, g = t & 7;
    {
      float4 s4a = adj4[n * ASQ + g];
      float4 s4b = adj4[n * ASQ + g + 8];
      float s = s4a.x + s4a.y + s4a.z + s4a.w + s4b.x + s4b.y + s4b.z + s4b.w;
      for (int off = 4; off; off >>= 1) s += __shfl_xor(s, off);
      if (g == 0) rinv2_s[n] = 1.0f / s;
    }
    float acc = 0.f;
    const float4* g1 = (const float4*)(gw1T + g * FS);
    for (int hc = 0; hc < 32; ++hc) macc(acc, buf4[n * FSQ + hc], g1[hc]);
    t1T[g * AS + n] = acc * rinv_s[n];
  }
  __syncthreads();

  // ---- P4: h = relu(rinv2*(adj@t1) + gb1) ----
  {
    const int n = t >> 3, j = t & 7;
    float acc = 0.f;
    const float4* ar = adj4 + n * ASQ;
    const float4* tr = (const float4*)(t1T + j * AS);
    for (int mq = 0; mq < 16; ++mq) macc(acc, ar[mq], tr[mq]);
    hT[j * AS + n] = fmaxf(acc * rinv2_s[n] + gb1s[j], 0.0f);
  }
  __syncthreads();

  // ---- P5: g = rinv2*(adj@h) ----
  {
    const int n = t >> 3, j = t & 7;
    float acc = 0.f;
    const float4* ar = adj4 + n * ASQ;
    const float4* hr = (const float4*)(hT + j * AS);
    for (int mq = 0; mq < 16; ++mq) macc(acc, ar[mq], hr[mq]);
    gsm[n * 8 + j] = acc * rinv2_s[n];
  }
  __syncthreads();

  // ---- P6: f_out = g @ gw2 + gb2 -> global ws ----
  {
    const float4* w4 = (const float4*)gw2s;
    float4 w[8];
#pragma unroll
    for (int j = 0; j < 8; ++j) w[j] = w4[j * 32 + hq];
    float4 bquad = ((const float4*)gb2s)[hq];
    const float4* g4 = (const float4*)gsm;
    float4* Fb4 = (float4*)Fb;
#pragma unroll
    for (int i = 0; i < 4; ++i) {
      int n = o0 + i;
      float4 g0 = g4[n * 2], g1 = g4[n * 2 + 1];
      float4 acc = bquad;
      fma4(acc, g0.x, w[0]); fma4(acc, g0.y, w[1]); fma4(acc, g0.z, w[2]); fma4(acc, g0.w, w[3]);
      fma4(acc, g1.x, w[4]); fma4(acc, g1.y, w[5]); fma4(acc, g1.z, w[6]); fma4(acc, g1.w, w[7]);
      Fb4[n * 32 + hq] = acc;
    }
  }
}

// ================= K2: one block per batch: ProbSparse attention =================
__global__ __launch_bounds__(1024, 4) void k2_attn(
    const float* __restrict__ x, const float* __restrict__ F,
    const float* __restrict__ gammap, const int* __restrict__ idxg,
    float* __restrict__ out, int B)
{
  const int b = blockIdx.x, tid = threadIdx.x;
  const float* xb = x + (size_t)b * 8192;
  float* outb = out + (size_t)b * 8192;

  __shared__ __align__(16) float fq[64 * FS];
  __shared__ __align__(16) float fk[64 * FS];
  __shared__ __align__(16) float fv[64 * FS];
  __shared__ __align__(16) float qks[64 * 26];
  __shared__ __align__(16) float sc[25 * AS];
  __shared__ float Ms[64];
  __shared__ int idxs[3200];
  __shared__ int mtop[25];
  __shared__ int repl[64];

  float4* fq4 = (float4*)fq;
  float4* fk4 = (float4*)fk;
  float4* fv4 = (float4*)fv;

  // ---- C0: stage q,k,v (from ws) and index_sample ----
  {
    const float4* Qg = (const float4*)(F + (size_t)b * 8192);
    const float4* Kg = (const float4*)(F + ((size_t)B + b) * 8192);
    const float4* Vg = (const float4*)(F + ((size_t)2 * B + b) * 8192);
    for (int i = tid; i < 2048; i += 1024) {
      int r = i >> 5, cq = i & 31;
      fq4[r * FSQ + cq] = Qg[i];
      fk4[r * FSQ + cq] = Kg[i];
      fv4[r * FSQ + cq] = Vg[i];
    }
    int4* id4 = (int4*)idxs;
    const int4* ig4 = (const int4*)idxg;
    for (int i = tid; i < 800; i += 1024) id4[i] = ig4[i];
  }
  __syncthreads();

  // ---- C1: qk_sample[n][s] = sum_l q[n][l]*k[n][idx[l][s]] ----
  if (tid < 512) {
    int n = tid >> 3, g = tid & 7;
    float a0 = 0.f, a1 = 0.f, a2 = 0.f, a3 = 0.f;
    const float4* q4 = (const float4*)(fq + n * FS);
    const float* kr = fk + n * FS;
    for (int lq = 0; lq < 32; ++lq) {
      float4 qv = q4[lq];
      const float* qp = (const float*)&qv;
#pragma unroll
      for (int ll = 0; ll < 4; ++ll) {
        const int* ip = idxs + (lq * 4 + ll) * 25;
        float qs = qp[ll];
        a0 = fmaf(qs, kr[ip[g]], a0);
        a1 = fmaf(qs, kr[ip[g + 8]], a1);
        a2 = fmaf(qs, kr[ip[g + 16]], a2);
        if (g == 0) a3 = fmaf(qs, kr[ip[24]], a3);
      }
    }
    qks[n * 26 + g] = a0;
    qks[n * 26 + g + 8] = a1;
    qks[n * 26 + g + 16] = a2;
    if (g == 0) qks[n * 26 + 24] = a3;
  }
  __syncthreads();

  // ---- C2: M, then top-25 (value desc, index asc) on wave 0 ----
  if (tid < 64) {
    float mx = -INFINITY, su = 0.f;
#pragma unroll
    for (int s = 0; s < 25; ++s) {
      float v = qks[tid * 26 + s];
      mx = fmaxf(mx, v);
      su += v;
    }
    Ms[tid] = mx - su * (1.0f / 128.0f);
    repl[tid] = 0;
    float v = Ms[tid];
    for (int it = 0; it < 25; ++it) {
      float bv2 = v;
      int bi = tid;
#pragma unroll
      for (int off = 32; off > 0; off >>= 1) {
        float ov = __shfl_xor(bv2, off);
        int oi = __shfl_xor(bi, off);
        if (ov > bv2 || (ov == bv2 && oi < bi)) { bv2 = ov; bi = oi; }
      }
      if (tid == 0) mtop[it] = bi;
      if (tid == bi) v = -INFINITY;
    }
  }
  __syncthreads();
  if (tid < 25) repl[mtop[tid]] = 1;
  __syncthreads();

  // ---- C4: dense scores, broadcast form (lane = n, conflict-free) ----
  {
    const int w16 = tid >> 6, n = tid & 63;
    const float scale = 0.08838834764831845f;
    int u1 = w16 + 16;
    bool has1 = (u1 < 25);
    int r0 = mtop[w16];
    int r1 = has1 ? mtop[u1] : 0;
    float acc0 = 0.f, acc1 = 0.f;
    for (int hc = 0; hc < 32; ++hc) {
      float4 kv = fk4[n * FSQ + hc];
      float4 q0 = fq4[r0 * FSQ + hc];
      macc(acc0, q0, kv);
      if (has1) {
        float4 q1 = fq4[r1 * FSQ + hc];
        macc(acc1, q1, kv);
      }
    }
    sc[w16 * AS + n] = acc0 * scale;
    if (has1) sc[u1 * AS + n] = acc1 * scale;
  }
  __syncthreads();

  // ---- C5: softmax over n (16 lanes per selected row) ----
  if (tid < 400) {
    int u = tid >> 4, g = tid & 15;
    float4* s4 = (float4*)(sc + u * AS);
    float4 v = s4[g];
    float mx = fmaxf(fmaxf(v.x, v.y), fmaxf(v.z, v.w));
    for (int off = 8; off; off >>= 1) mx = fmaxf(mx, __shfl_xor(mx, off));
    float4 e;
    e.x = __expf(v.x - mx); e.y = __expf(v.y - mx);
    e.z = __expf(v.z - mx); e.w = __expf(v.w - mx);
    float su = e.x + e.y + e.z + e.w;
    for (int off = 8; off; off >>= 1) su += __shfl_xor(su, off);
    float inv = 1.0f / su;
    e.x *= inv; e.y *= inv; e.z *= inv; e.w *= inv;
    s4[g] = e;
  }
  __syncthreads();

  // ---- C6: upd rows (threads 0..799) || cumsum rows (threads 832..959) ----
  const float gamma = *gammap;
  if (tid < 800) {
    int u = tid >> 5, hqq = tid & 31;
    int row = mtop[u];
    float4 acc = make_float4(0.f, 0.f, 0.f, 0.f);
    const float* scr = sc + u * AS;
    for (int n = 0; n < 64; ++n) fma4(acc, scr[n], fv4[n * FSQ + hqq]);
    const float4* xg = (const float4*)xb;
    float4* og = (float4*)outb;
    float4 xr = xg[row * 32 + hqq];
    og[row * 32 + hqq] = make_float4(fmaf(gamma, acc.x, xr.x), fmaf(gamma, acc.y, xr.y),
                                     fmaf(gamma, acc.z, xr.z), fmaf(gamma, acc.w, xr.w));
  } else if (tid >= 832 && tid < 960) {
    int h = tid - 832;
    float acc = 0.f;
    for (int n = 0; n < 64; ++n) {
      acc += fv[n * FS + h];
      if (!repl[n]) outb[n * 128 + h] = fmaf(gamma, acc, xb[n * 128 + h]);
    }
  }
}

// ================= Fallback: round-2 monolith (used when ws too small) =================
__global__ __launch_bounds__(1024) void gcn_ssa_mono(
    const float* __restrict__ x,
    const float* __restrict__ wq, const float* __restrict__ bq,
    const float* __restrict__ wk, const float* __restrict__ bk,
    const float* __restrict__ wv, const float* __restrict__ bv,
    const float* __restrict__ gw1, const float* __restrict__ gb1,
    const float* __restrict__ gw2, const float* __restrict__ gb2,
    const float* __restrict__ gammap, const int* __restrict__ idxg,
    float* __restrict__ out)
{
  const int b = blockIdx.x, tid = threadIdx.x;
  const float* xb = x + (size_t)b * 8192;
  float* outb = out + (size_t)b * 8192;

  __shared__ __align__(16) float fq[64 * FS];
  __shared__ __align__(16) float fk[64 * FS];
  __shared__ __align__(16) float fv[64 * FS];
  __shared__ __align__(16) float U[12480];
  __shared__ __align__(16) float gw1T[8 * FS];
  __shared__ __align__(16) float gw2s[8 * 128];
  __shared__ __align__(16) float gb1s[8];
  __shared__ __align__(16) float gb2s[128];
  __shared__ float rinv_s[64], nrm_s[64], rinv2_s[64], Ms[64];
  __shared__ int mtop[25], repl[64];

  float4* fq4 = (float4*)fq;
  float4* fk4 = (float4*)fk;
  float4* fv4 = (float4*)fv;
  float4* U4 = (float4*)U;

  {
    const float4* xg = (const float4*)xb;
    for (int i = tid; i < 2048; i += 1024) {
      int r = i >> 5, cq = i & 31;
      fv4[r * FSQ + cq] = xg[i];
    }
    const float4* wqg = (const float4*)wq;
    const float4* wkg = (const float4*)wk;
    const float4* wvg = (const float4*)wv;
    for (int i = tid; i < 1024; i += 1024) {
      U4[i] = wqg[i];
      U4[1024 + i] = wkg[i];
      U4[2048 + i] = wvg[i];
    }
    if (tid < 64) {
      U[12288 + tid] = bq[tid];
      U[12352 + tid] = bk[tid];
      U[12416 + tid] = bv[tid];
    }
    for (int i = tid; i < 1024; i += 1024) {
      int h = i >> 3, j = i & 7;
      gw1T[j * FS + h] = gw1[i];
      gw2s[i] = gw2[i];
    }
    if (tid < 8) gb1s[tid] = gb1[tid];
    if (tid < 128) gb2s[tid] = gb2[tid];
  }
  __syncthreads();

  float4 vacc0, vacc1;
  {
    const int o0 = (tid >> 5) << 1;
    const int hq = tid & 31;
    const float4* wqs = U4;
    const float4* wks = U4 + 1024;
    const float4* wvs = U4 + 2048;
    float4 aq0, aq1, ak0, ak1, av0, av1;
    {
      float bq0 = U[12288 + o0], bq1 = U[12288 + o0 + 1];
      float bk0 = U[12352 + o0], bk1 = U[12352 + o0 + 1];
      float bv0 = U[12416 + o0], bv1 = U[12416 + o0 + 1];
      aq0 = make_float4(bq0, bq0, bq0, bq0); aq1 = make_float4(bq1, bq1, bq1, bq1);
      ak0 = make_float4(bk0, bk0, bk0, bk0); ak1 = make_float4(bk1, bk1, bk1, bk1);
      av0 = make_float4(bv0, bv0, bv0, bv0); av1 = make_float4(bv1, bv1, bv1, bv1);
    }
    for (int cq = 0; cq < 16; ++cq) {
      float4 x0 = fv4[(4 * cq + 0) * FSQ + hq];
      float4 x1 = fv4[(4 * cq + 1) * FSQ + hq];
      float4 x2 = fv4[(4 * cq + 2) * FSQ + hq];
      float4 x3 = fv4[(4 * cq + 3) * FSQ + hq];
      float4 w;
      w = wqs[o0 * 16 + cq];       fma4(aq0, w.x, x0); fma4(aq0, w.y, x1); fma4(aq0, w.z, x2); fma4(aq0, w.w, x3);
      w = wqs[(o0 + 1) * 16 + cq]; fma4(aq1, w.x, x0); fma4(aq1, w.y, x1); fma4(aq1, w.z, x2); fma4(aq1, w.w, x3);
      w = wks[o0 * 16 + cq];       fma4(ak0, w.x, x0); fma4(ak0, w.y, x1); fma4(ak0, w.z, x2); fma4(ak0, w.w, x3);
      w = wks[(o0 + 1) * 16 + cq]; fma4(ak1, w.x, x0); fma4(ak1, w.y, x1); fma4(ak1, w.z, x2); fma4(ak1, w.w, x3);
      w = wvs[o0 * 16 + cq];       fma4(av0, w.x, x0); fma4(av0, w.y, x1); fma4(av0, w.z, x2); fma4(av0, w.w, x3);
      w = wvs[(o0 + 1) * 16 + cq]; fma4(av1, w.x, x0); fma4(av1, w.y, x1); fma4(av1, w.z, x2); fma4(av1, w.w, x3);
    }
    fq4[o0 * FSQ + hq] = aq0;
    fq4[(o0 + 1) * FSQ + hq] = aq1;
    fk4[o0 * FSQ + hq] = ak0;
    fk4[(o0 + 1) * FSQ + hq] = ak1;
    vacc0 = av0; vacc1 = av1;
  }
  __syncthreads();
  {
    const int o0 = (tid >> 5) << 1, hq = tid & 31;
    fv4[o0 * FSQ + hq] = vacc0;
    fv4[(o0 + 1) * FSQ + hq] = vacc1;
  }
  int* idxs = (int*)(U + 7616);
  for (int i = tid; i < 3200; i += 1024) idxs[i] = idxg[i];
  __syncthreads();

  float* adjb = U;
  float* t1T = U + 4352;
  float* hT  = U + 4896;
  float* gsm = U + 5440;
  float* qks = U + 5952;
  float4* adj4 = (float4*)adjb;

  for (int brr = 0; brr < 3; ++brr) {
    float* f = (brr == 0) ? fq : (brr == 1) ? fk : fv;
    float4* f4 = (float4*)f;

    {
      int row = tid >> 4, g = tid & 15;
      float4 aa = f4[row * FSQ + 2 * g];
      float4 c = f4[row * FSQ + 2 * g + 1];
      float s0 = aa.x + aa.y + aa.z + aa.w + c.x + c.y + c.z + c.w;
      float s1 = aa.x * aa.x + aa.y * aa.y + aa.z * aa.z + aa.w * aa.w +
                 c.x * c.x + c.y * c.y + c.z * c.z + c.w * c.w;
      for (int off = 8; off; off >>= 1) {
        s0 += __shfl_xor(s0, off);
        s1 += __shfl_xor(s1, off);
      }
      if (g == 0) {
        rinv_s[row] = (s0 == 0.0f) ? 0.0f : (1.0f / s0);
        nrm_s[row] = 1.0f / fmaxf(sqrtf(s1), 1e-8f);
      }
    }
    __syncthreads();

    if (tid < 256) {
      int rq = tid >> 4, q = tid & 15;
      int r0 = rq * 4;
      float acc[4][4];
#pragma unroll
      for (int i = 0; i < 4; ++i)
#pragma unroll
        for (int j = 0; j < 4; ++j) acc[i][j] = 0.0f;
      for (int hc = 0; hc < 32; ++hc) {
        float4 a0 = f4[(r0 + 0) * FSQ + hc];
        float4 a1 = f4[(r0 + 1) * FSQ + hc];
        float4 a2 = f4[(r0 + 2) * FSQ + hc];
        float4 a3 = f4[(r0 + 3) * FSQ + hc];
        float4 b0 = f4[q * FSQ + hc];
        float4 b1 = f4[(q + 16) * FSQ + hc];
        float4 b2 = f4[(q + 32) * FSQ + hc];
        float4 b3 = f4[(q + 48) * FSQ + hc];
        macc(acc[0][0], a0, b0); macc(acc[0][1], a0, b1); macc(acc[0][2], a0, b2); macc(acc[0][3], a0, b3);
        macc(acc[1][0], a1, b0); macc(acc[1][1], a1, b1); macc(acc[1][2], a1, b2); macc(acc[1][3], a1, b3);
        macc(acc[2][0], a2, b0); macc(acc[2][1], a2, b1); macc(acc[2][2], a2, b2); macc(acc[2][3], a2, b3);
        macc(acc[3][0], a3, b0); macc(acc[3][1], a3, b1); macc(acc[3][2], a3, b2); macc(acc[3][3], a3, b3);
      }
#pragma unroll
      for (int i = 0; i < 4; ++i) {
        int r = r0 + i;
        float nr = nrm_s[r];
#pragma unroll
        for (int j = 0; j < 4; ++j) {
          int m = q + 16 * j;
          float sim = acc[i][j] * nr * nrm_s[m];
          float aa = (sim > 0.5f) ? 1.0f : 0.0f;
          if (r == m) aa += 1.0f;
          adjb[r * AS + m] = aa;
        }
      }
    }
    __syncthreads();

    {
      int row = tid >> 4, g = tid & 15;
      float4 aa = adj4[row * ASQ + g];
      float s = aa.x + aa.y + aa.z + aa.w;
      for (int off = 8; off; off >>= 1) s += __shfl_xor(s, off);
      if (g == 0) rinv2_s[row] = 1.0f / s;
    }
    if (tid >= 512 && tid < 768) {
      int lt = tid - 512;
      int n = lt >> 2, j0 = (lt & 3) * 2;
      float a0 = 0.f, a1 = 0.f;
      const float4* w0 = (const float4*)(gw1T + j0 * FS);
      const float4* w1 = (const float4*)(gw1T + (j0 + 1) * FS);
      for (int hc = 0; hc < 32; ++hc) {
        float4 fx = f4[n * FSQ + hc];
        macc(a0, fx, w0[hc]);
        macc(a1, fx, w1[hc]);
      }
      float rv = rinv_s[n];
      t1T[j0 * AS + n] = a0 * rv;
      t1T[(j0 + 1) * AS + n] = a1 * rv;
    }
    __syncthreads();

    if (tid < 512) {
      int n = tid >> 3, j = tid & 7;
      float acc = 0.f;
      const float4* a4 = (const float4*)(adjb + n * AS);
      const float4* t4 = (const float4*)(t1T + j * AS);
      for (int mq = 0; mq < 16; ++mq) macc(acc, a4[mq], t4[mq]);
      hT[j * AS + n] = fmaxf(acc * rinv2_s[n] + gb1s[j], 0.0f);
    }
    __syncthreads();

    if (tid < 512) {
      int n = tid >> 3, j = tid & 7;
      float acc = 0.f;
      const float4* a4 = (const float4*)(adjb + n * AS);
      const float4* h4 = (const float4*)(hT + j * AS);
      for (int mq = 0; mq < 16; ++mq) macc(acc, a4[mq], h4[mq]);
      gsm[n * 8 + j] = acc * rinv2_s[n];
    }
    __syncthreads();

    {
      int n0 = tid >> 5, hq = tid & 31;
      int n1 = n0 + 32;
      const float4* g4 = (const float4*)gsm;
      float4 ga0 = g4[n0 * 2], ga1 = g4[n0 * 2 + 1];
      float4 gc0 = g4[n1 * 2], gc1 = g4[n1 * 2 + 1];
      const float* pa0 = (const float*)&ga0;
      const float* pa1 = (const float*)&ga1;
      const float* pc0 = (const float*)&gc0;
      const float* pc1 = (const float*)&gc1;
      const float4* w4 = (const float4*)gw2s;
      float4 bquad = ((const float4*)gb2s)[hq];
      float4 acc0 = bquad, acc1 = bquad;
#pragma unroll
      for (int j = 0; j < 4; ++j) {
        float4 w = w4[j * 32 + hq];
        fma4(acc0, pa0[j], w);
        fma4(acc1, pc0[j], w);
      }
#pragma unroll
      for (int j = 0; j < 4; ++j) {
        float4 w = w4[(j + 4) * 32 + hq];
        fma4(acc0, pa1[j], w);
        fma4(acc1, pc1[j], w);
      }
      f4[n0 * FSQ + hq] = acc0;
      f4[n1 * FSQ + hq] = acc1;
    }
    __syncthreads();
  }

  if (tid < 512) {
    int n = tid >> 3, g = tid & 7;
    float a0 = 0.f, a1 = 0.f, a2 = 0.f, a3 = 0.f;
    const float4* q4 = (const float4*)(fq + n * FS);
    const float* kr = fk + n * FS;
    for (int lq = 0; lq < 32; ++lq) {
      float4 qv = q4[lq];
      const float* qp = (const float*)&qv;
#pragma unroll
      for (int ll = 0; ll < 4; ++ll) {
        const int* ip = idxs + (lq * 4 + ll) * 25;
        float qs = qp[ll];
        a0 = fmaf(qs, kr[ip[g]], a0);
        a1 = fmaf(qs, kr[ip[g + 8]], a1);
        a2 = fmaf(qs, kr[ip[g + 16]], a2);
        if (g == 0) a3 = fmaf(qs, kr[ip[24]], a3);
      }
    }
    qks[n * 26 + g] = a0;
    qks[n * 26 + g + 8] = a1;
    qks[n * 26 + g + 16] = a2;
    if (g == 0) qks[n * 26 + 24] = a3;
  }
  __syncthreads();
  if (tid < 64) {
    float mx = -INFINITY, su = 0.f;
#pragma unroll
    for (int s = 0; s < 25; ++s) {
      float v = qks[tid * 26 + s];
      mx = fmaxf(mx, v);
      su += v;
    }
    Ms[tid] = mx - su * (1.0f / 128.0f);
    repl[tid] = 0;
  }
  __syncthreads();
  if (tid < 64) {
    float v = Ms[tid];
    for (int it = 0; it < 25; ++it) {
      float bv2 = v;
      int bi = tid;
#pragma unroll
      for (int off = 32; off > 0; off >>= 1) {
        float ov = __shfl_xor(bv2, off);
        int oi = __shfl_xor(bi, off);
        if (ov > bv2 || (ov == bv2 && oi < bi)) { bv2 = ov; bi = oi; }
      }
      if (tid == 0) mtop[it] = bi;
      if (tid == bi) v = -INFINITY;
    }
  }
  __syncthreads();
  if (tid < 25) repl[mtop[tid]] = 1;
  __syncthreads();

  float* scm = U;
  if (tid < 256) {
    const int w = tid >> 6, n = tid & 63;
    const float scale = 0.08838834764831845f;
    int rows[7];
#pragma unroll
    for (int t2 = 0; t2 < 7; ++t2) {
      int u = w + 4 * t2;
      rows[t2] = (u < 25) ? mtop[u] : 0;
    }
    float acc[7] = {0.f, 0.f, 0.f, 0.f, 0.f, 0.f, 0.f};
    for (int hq2 = 0; hq2 < 32; ++hq2) {
      float4 kv = fk4[n * FSQ + hq2];
#pragma unroll
      for (int t2 = 0; t2 < 7; ++t2) {
        int u = w + 4 * t2;
        if (u < 25) {
          float4 qv = fq4[rows[t2] * FSQ + hq2];
          acc[t2] = fmaf(qv.x, kv.x, acc[t2]);
          acc[t2] = fmaf(qv.y, kv.y, acc[t2]);
          acc[t2] = fmaf(qv.z, kv.z, acc[t2]);
          acc[t2] = fmaf(qv.w, kv.w, acc[t2]);
        }
      }
    }
#pragma unroll
    for (int t2 = 0; t2 < 7; ++t2) {
      int u = w + 4 * t2;
      if (u < 25) scm[u * AS + n] = acc[t2] * scale;
    }
  }
  __syncthreads();
  if (tid < 400) {
    int u = tid >> 4, g = tid & 15;
    float4* s4 = (float4*)(scm + u * AS);
    float4 v = s4[g];
    float mx = fmaxf(fmaxf(v.x, v.y), fmaxf(v.z, v.w));
    for (int off = 8; off; off >>= 1) mx = fmaxf(mx, __shfl_xor(mx, off));
    float4 e;
    e.x = __expf(v.x - mx); e.y = __expf(v.y - mx);
    e.z = __expf(v.z - mx); e.w = __expf(v.w - mx);
    float su = e.x + e.y + e.z + e.w;
    for (int off = 8; off; off >>= 1) su += __shfl_xor(su, off);
    float inv = 1.0f / su;
    e.x *= inv; e.y *= inv; e.z *= inv; e.w *= inv;
    s4[g] = e;
  }
  __syncthreads();

  const float gamma = *gammap;
  if (tid < 416) {
    int up = tid >> 5, hq = tid & 31;
    int u0 = up * 2, u1 = u0 + 1;
    bool has1 = (u1 < 25);
    int r0 = mtop[u0];
    int r1 = has1 ? mtop[u1] : 0;
    float4 a0 = make_float4(0.f, 0.f, 0.f, 0.f);
    float4 a1 = make_float4(0.f, 0.f, 0.f, 0.f);
    for (int n = 0; n < 64; ++n) {
      float4 vv = fv4[n * FSQ + hq];
      fma4(a0, scm[u0 * AS + n], vv);
      if (has1) fma4(a1, scm[u1 * AS + n], vv);
    }
    const float4* xg = (const float4*)xb;
    float4* og = (float4*)outb;
    float4 xr = xg[r0 * 32 + hq];
    og[r0 * 32 + hq] = make_float4(fmaf(gamma, a0.x, xr.x), fmaf(gamma, a0.y, xr.y),
                                   fmaf(gamma, a0.z, xr.z), fmaf(gamma, a0.w, xr.w));
    if (has1) {
      float4 xr1 = xg[r1 * 32 + hq];
      og[r1 * 32 + hq] = make_float4(fmaf(gamma, a1.x, xr1.x), fmaf(gamma, a1.y, xr1.y),
                                     fmaf(gamma, a1.z, xr1.z), fmaf(gamma, a1.w, xr1.w));
    }
  } else if (tid >= 512 && tid < 640) {
    int h = tid - 512;
    float acc = 0.f;
    for (int n = 0; n < 64; ++n) {
      acc += fv[n * FS + h];
      if (!repl[n]) outb[n * 128 + h] = fmaf(gamma, acc, xb[n * 128 + h]);
    }
  }
}

extern "C" void kernel_launch(void* const* d_in, const int* in_sizes, int n_in,
                              void* d_out, int out_size, void* d_ws, size_t ws_size,
                              hipStream_t stream) {
  const float* x   = (const float*)d_in[0];
  const float* wq  = (const float*)d_in[1];
  const float* bq  = (const float*)d_in[2];
  const float* wk  = (const float*)d_in[3];
  const float* bk  = (const float*)d_in[4];
  const float* wv  = (const float*)d_in[5];
  const float* bv  = (const float*)d_in[6];
  const float* gw1 = (const float*)d_in[7];
  const float* gb1 = (const float*)d_in[8];
  const float* gw2 = (const float*)d_in[9];
  const float* gb2 = (const float*)d_in[10];
  const float* gm  = (const float*)d_in[11];
  const int* idx   = (const int*)d_in[12];
  float* out = (float*)d_out;
  int B = in_sizes[0] / (64 * 128);

  size_t need = (size_t)3 * B * 8192 * sizeof(float);
  if (ws_size >= need) {
    float* F = (float*)d_ws;
    hipLaunchKernelGGL(k1_branch, dim3(3 * B), dim3(512), 0, stream,
                       x, wq, bq, wk, bk, wv, bv, gw1, gb1, gw2, gb2, F, B);
    hipLaunchKernelGGL(k2_attn, dim3(B), dim3(1024), 0, stream,
                       x, F, gm, idx, out, B);
  } else {
    hipLaunchKernelGGL(gcn_ssa_mono, dim3(B), dim3(1024), 0, stream,
                       x, wq, bq, wk, bk, wv, bv, gw1, gb1, gw2, gb2, gm, idx, out);
  }
}

// Round 5
// 334.874 us; speedup vs baseline: 1.6089x; 1.6089x over previous
//
#include <hip/hip_runtime.h>
#include <math.h>

#define T 1024
#define FS 132   // feature row stride (floats), float4-aligned, odd quad stride
#define FSQ 33   // in float4
#define AS 68    // adj/score row stride
#define ASQ 17

__device__ __forceinline__ void macc(float& acc, const float4 a, const float4 b) {
  acc = fmaf(a.x, b.x, acc);
  acc = fmaf(a.y, b.y, acc);
  acc = fmaf(a.z, b.z, acc);
  acc = fmaf(a.w, b.w, acc);
}
__device__ __forceinline__ void fma4(float4& a, float s, const float4 b) {
  a.x = fmaf(s, b.x, a.x);
  a.y = fmaf(s, b.y, a.y);
  a.z = fmaf(s, b.z, a.z);
  a.w = fmaf(s, b.w, a.w);
}

__global__ __launch_bounds__(T) void gcn_ssa_kernel(
    const float* __restrict__ x,
    const float* __restrict__ wq, const float* __restrict__ bq,
    const float* __restrict__ wk, const float* __restrict__ bk,
    const float* __restrict__ wv, const float* __restrict__ bv,
    const float* __restrict__ gw1, const float* __restrict__ gb1,
    const float* __restrict__ gw2, const float* __restrict__ gb2,
    const float* __restrict__ gammap, const int* __restrict__ idxg,
    float* __restrict__ out)
{
  const int b = blockIdx.x, tid = threadIdx.x;
  const float* xb = x + (size_t)b * 8192;
  float* outb = out + (size_t)b * 8192;

  __shared__ __align__(16) float fq[64 * FS];
  __shared__ __align__(16) float fk[64 * FS];
  __shared__ __align__(16) float fv[64 * FS];
  __shared__ __align__(16) float U[12480];      // weights | adj/t1T/hT/gsm | kT/P | sc
  __shared__ __align__(16) float gw1T[8 * FS];  // gw1 transposed [j][h]
  __shared__ __align__(16) float gw2s[8 * 128];
  __shared__ __align__(16) float gb1s[8];
  __shared__ __align__(16) float gb2s[128];
  __shared__ float rinv_s[64], nrm_s[64], rinv2_s[64];
  __shared__ int mtop[25];

  float4* fq4 = (float4*)fq;
  float4* fk4 = (float4*)fk;
  float4* fv4 = (float4*)fv;
  float4* U4 = (float4*)U;

  // ---------------- Stage A0: stage x (into fv, stride FS) + weights ----------------
  {
    const float4* xg = (const float4*)xb;
    for (int i = tid; i < 2048; i += T) {
      int r = i >> 5, cq = i & 31;
      fv4[r * FSQ + cq] = xg[i];
    }
    const float4* wqg = (const float4*)wq;
    const float4* wkg = (const float4*)wk;
    const float4* wvg = (const float4*)wv;
    for (int i = tid; i < 1024; i += T) {
      U4[i] = wqg[i];
      U4[1024 + i] = wkg[i];
      U4[2048 + i] = wvg[i];
    }
    if (tid < 64) {
      U[12288 + tid] = bq[tid];
      U[12352 + tid] = bk[tid];
      U[12416 + tid] = bv[tid];
    }
    for (int i = tid; i < 1024; i += T) {
      int h = i >> 3, j = i & 7;
      gw1T[j * FS + h] = gw1[i];
      gw2s[i] = gw2[i];
    }
    if (tid < 8) gb1s[tid] = gb1[tid];
    if (tid < 128) gb2s[tid] = gb2[tid];
  }
  __syncthreads();

  // ---------------- Stage A1: projection q,k,v (2 o-rows x 4 h per thread) ----------------
  float4 vacc0, vacc1;
  {
    const int o0 = (tid >> 5) << 1;  // half-wave uniform
    const int hq = tid & 31;
    const float4* wqs = U4;
    const float4* wks = U4 + 1024;
    const float4* wvs = U4 + 2048;
    float4 aq0, aq1, ak0, ak1, av0, av1;
    {
      float bq0 = U[12288 + o0], bq1 = U[12288 + o0 + 1];
      float bk0 = U[12352 + o0], bk1 = U[12352 + o0 + 1];
      float bv0 = U[12416 + o0], bv1 = U[12416 + o0 + 1];
      aq0 = make_float4(bq0, bq0, bq0, bq0); aq1 = make_float4(bq1, bq1, bq1, bq1);
      ak0 = make_float4(bk0, bk0, bk0, bk0); ak1 = make_float4(bk1, bk1, bk1, bk1);
      av0 = make_float4(bv0, bv0, bv0, bv0); av1 = make_float4(bv1, bv1, bv1, bv1);
    }
    for (int cq = 0; cq < 16; ++cq) {
      float4 x0 = fv4[(4 * cq + 0) * FSQ + hq];
      float4 x1 = fv4[(4 * cq + 1) * FSQ + hq];
      float4 x2 = fv4[(4 * cq + 2) * FSQ + hq];
      float4 x3 = fv4[(4 * cq + 3) * FSQ + hq];
      float4 w;
      w = wqs[o0 * 16 + cq];       fma4(aq0, w.x, x0); fma4(aq0, w.y, x1); fma4(aq0, w.z, x2); fma4(aq0, w.w, x3);
      w = wqs[(o0 + 1) * 16 + cq]; fma4(aq1, w.x, x0); fma4(aq1, w.y, x1); fma4(aq1, w.z, x2); fma4(aq1, w.w, x3);
      w = wks[o0 * 16 + cq];       fma4(ak0, w.x, x0); fma4(ak0, w.y, x1); fma4(ak0, w.z, x2); fma4(ak0, w.w, x3);
      w = wks[(o0 + 1) * 16 + cq]; fma4(ak1, w.x, x0); fma4(ak1, w.y, x1); fma4(ak1, w.z, x2); fma4(ak1, w.w, x3);
      w = wvs[o0 * 16 + cq];       fma4(av0, w.x, x0); fma4(av0, w.y, x1); fma4(av0, w.z, x2); fma4(av0, w.w, x3);
      w = wvs[(o0 + 1) * 16 + cq]; fma4(av1, w.x, x0); fma4(av1, w.y, x1); fma4(av1, w.z, x2); fma4(av1, w.w, x3);
    }
    fq4[o0 * FSQ + hq] = aq0;
    fq4[(o0 + 1) * FSQ + hq] = aq1;
    fk4[o0 * FSQ + hq] = ak0;
    fk4[(o0 + 1) * FSQ + hq] = ak1;
    vacc0 = av0; vacc1 = av1;
  }
  __syncthreads();
  {
    const int o0 = (tid >> 5) << 1, hq = tid & 31;
    fv4[o0 * FSQ + hq] = vacc0;
    fv4[(o0 + 1) * FSQ + hq] = vacc1;
  }
  __syncthreads();

  float* adjb = U;           // 64*68 = 4352 floats
  float* t1T = U + 4352;     // 8*68  [j][m]
  float* hT  = U + 4896;     // 8*68  [j][m]
  float* gsm = U + 5440;     // 64*8  [n][j]
  float4* adj4 = (float4*)adjb;

  // ---------------- Stage B: three GCN branches ----------------
  for (int brr = 0; brr < 3; ++brr) {
    float* f = (brr == 0) ? fq : (brr == 1) ? fk : fv;
    float4* f4 = (float4*)f;

    // phase1: row sum + sumsq (16 lanes per row)
    {
      int row = tid >> 4, g = tid & 15;
      float4 aa = f4[row * FSQ + 2 * g];
      float4 c = f4[row * FSQ + 2 * g + 1];
      float s0 = aa.x + aa.y + aa.z + aa.w + c.x + c.y + c.z + c.w;
      float s1 = aa.x * aa.x + aa.y * aa.y + aa.z * aa.z + aa.w * aa.w +
                 c.x * c.x + c.y * c.y + c.z * c.z + c.w * c.w;
      for (int off = 8; off; off >>= 1) {
        s0 += __shfl_xor(s0, off);
        s1 += __shfl_xor(s1, off);
      }
      if (g == 0) {
        rinv_s[row] = (s0 == 0.0f) ? 0.0f : (1.0f / s0);
        nrm_s[row] = 1.0f / fmaxf(sqrtf(s1), 1e-8f);
      }
    }
    __syncthreads();

    // phase2: gram (threads 0-255, 4x4 tile) || t1 (threads 512-767)
    if (tid < 256) {
      int rq = tid >> 4, q = tid & 15;
      int r0 = rq * 4;
      float acc[4][4];
#pragma unroll
      for (int i = 0; i < 4; ++i)
#pragma unroll
        for (int j = 0; j < 4; ++j) acc[i][j] = 0.0f;
      for (int hc = 0; hc < 32; ++hc) {
        float4 a0 = f4[(r0 + 0) * FSQ + hc];
        float4 a1 = f4[(r0 + 1) * FSQ + hc];
        float4 a2 = f4[(r0 + 2) * FSQ + hc];
        float4 a3 = f4[(r0 + 3) * FSQ + hc];
        float4 b0 = f4[q * FSQ + hc];
        float4 b1 = f4[(q + 16) * FSQ + hc];
        float4 b2 = f4[(q + 32) * FSQ + hc];
        float4 b3 = f4[(q + 48) * FSQ + hc];
        macc(acc[0][0], a0, b0); macc(acc[0][1], a0, b1); macc(acc[0][2], a0, b2); macc(acc[0][3], a0, b3);
        macc(acc[1][0], a1, b0); macc(acc[1][1], a1, b1); macc(acc[1][2], a1, b2); macc(acc[1][3], a1, b3);
        macc(acc[2][0], a2, b0); macc(acc[2][1], a2, b1); macc(acc[2][2], a2, b2); macc(acc[2][3], a2, b3);
        macc(acc[3][0], a3, b0); macc(acc[3][1], a3, b1); macc(acc[3][2], a3, b2); macc(acc[3][3], a3, b3);
      }
#pragma unroll
      for (int i = 0; i < 4; ++i) {
        int r = r0 + i;
        float nr = nrm_s[r];
#pragma unroll
        for (int j = 0; j < 4; ++j) {
          int m = q + 16 * j;
          float sim = acc[i][j] * nr * nrm_s[m];
          float aa = (sim > 0.5f) ? 1.0f : 0.0f;
          if (r == m) aa += 1.0f;
          adjb[r * AS + m] = aa;
        }
      }
    } else if (tid >= 512 && tid < 768) {
      int lt = tid - 512;
      int n = lt >> 2, j0 = (lt & 3) * 2;
      float a0 = 0.f, a1 = 0.f;
      const float4* w0 = (const float4*)(gw1T + j0 * FS);
      const float4* w1 = (const float4*)(gw1T + (j0 + 1) * FS);
      for (int hc = 0; hc < 32; ++hc) {
        float4 fx = f4[n * FSQ + hc];
        macc(a0, fx, w0[hc]);
        macc(a1, fx, w1[hc]);
      }
      float rv = rinv_s[n];
      t1T[j0 * AS + n] = a0 * rv;
      t1T[(j0 + 1) * AS + n] = a1 * rv;
    }
    __syncthreads();

    // phase3: adjacency row sums
    {
      int row = tid >> 4, g = tid & 15;
      float4 aa = adj4[row * ASQ + g];
      float s = aa.x + aa.y + aa.z + aa.w;
      for (int off = 8; off; off >>= 1) s += __shfl_xor(s, off);
      if (g == 0) rinv2_s[row] = 1.0f / s;
    }
    __syncthreads();

    // phase4: h = relu(rinv2*(adj@t1) + gb1)
    if (tid < 512) {
      int n = tid >> 3, j = tid & 7;
      float acc = 0.f;
      const float4* a4 = (const float4*)(adjb + n * AS);
      const float4* t4 = (const float4*)(t1T + j * AS);
      for (int mq = 0; mq < 16; ++mq) macc(acc, a4[mq], t4[mq]);
      hT[j * AS + n] = fmaxf(acc * rinv2_s[n] + gb1s[j], 0.0f);
    }
    __syncthreads();

    // phase5: g = rinv2*(adj@h)
    if (tid < 512) {
      int n = tid >> 3, j = tid & 7;
      float acc = 0.f;
      const float4* a4 = (const float4*)(adjb + n * AS);
      const float4* h4 = (const float4*)(hT + j * AS);
      for (int mq = 0; mq < 16; ++mq) macc(acc, a4[mq], h4[mq]);
      gsm[n * 8 + j] = acc * rinv2_s[n];
    }
    __syncthreads();

    // phase6: f = g @ gw2 + gb2 (in place)
    {
      int n0 = tid >> 5, hq = tid & 31;
      int n1 = n0 + 32;
      const float4* g4 = (const float4*)gsm;
      float4 ga0 = g4[n0 * 2], ga1 = g4[n0 * 2 + 1];
      float4 gc0 = g4[n1 * 2], gc1 = g4[n1 * 2 + 1];
      const float* pa0 = (const float*)&ga0;
      const float* pa1 = (const float*)&ga1;
      const float* pc0 = (const float*)&gc0;
      const float* pc1 = (const float*)&gc1;
      const float4* w4 = (const float4*)gw2s;
      float4 bquad = ((const float4*)gb2s)[hq];
      float4 acc0 = bquad, acc1 = bquad;
#pragma unroll
      for (int j = 0; j < 4; ++j) {
        float4 w = w4[j * 32 + hq];
        fma4(acc0, pa0[j], w);
        fma4(acc1, pc0[j], w);
      }
#pragma unroll
      for (int j = 0; j < 4; ++j) {
        float4 w = w4[(j + 4) * 32 + hq];
        fma4(acc0, pa1[j], w);
        fma4(acc1, pc1[j], w);
      }
      f4[n0 * FSQ + hq] = acc0;
      f4[n1 * FSQ + hq] = acc1;
    }
    __syncthreads();
  }

  // ---------------- kT build: kT[feature j][n] = fk[n][j], stride AS ----------------
  float* kT = U;             // 128*68 = 8704 floats (adj/t1T/hT/gsm dead)
  float* Pp = U + 8704;      // partials: 2 x 25 x 64 = 3200 floats
  {
    const int c = tid >> 6;  // 0..15 (wave-uniform)
    const int n = tid & 63;
    float4 v0 = fk4[n * FSQ + 2 * c];
    float4 v1 = fk4[n * FSQ + 2 * c + 1];
    const float* p0 = (const float*)&v0;
    const float* p1 = (const float*)&v1;
#pragma unroll
    for (int e = 0; e < 4; ++e) kT[(8 * c + e) * AS + n] = p0[e];
#pragma unroll
    for (int e = 0; e < 4; ++e) kT[(8 * c + 4 + e) * AS + n] = p1[e];
  }
  __syncthreads();

  // ---------------- qk_sample (threads 0-127) || cumsum-all rows (threads 128-255) ----------------
  const float gamma = *gammap;
  if (tid < 128) {
    const int w = tid >> 6, n = tid & 63;
    float acc[25];
#pragma unroll
    for (int s = 0; s < 25; ++s) acc[s] = 0.f;
    const float* qrow = fq + n * FS + w * 64;
    for (int lb = 0; lb < 16; ++lb) {
      float4 qv = *(const float4*)(qrow + 4 * lb);
      const float* qp = (const float*)&qv;
#pragma unroll
      for (int i = 0; i < 4; ++i) {
        const float qs = qp[i];
        // idx row base: wave-uniform -> force SGPR so idxg reads become s_loads
        const int base = __builtin_amdgcn_readfirstlane((w * 64 + 4 * lb + i) * 25);
#pragma unroll
        for (int s = 0; s < 25; ++s) {
          acc[s] = fmaf(qs, kT[idxg[base + s] * AS + n], acc[s]);
        }
      }
    }
    float* P = Pp + w * 1600;
#pragma unroll
    for (int s = 0; s < 25; ++s) P[s * 64 + n] = acc[s];
  } else if (tid < 256) {
    // cumsum for ALL rows; selected rows get overwritten by upd later
    const int h = tid - 128;
    float acc = 0.f;
    for (int n = 0; n < 64; ++n) {
      acc += fv[n * FS + h];
      outb[n * 128 + h] = fmaf(gamma, acc, xb[n * 128 + h]);
    }
  }
  __syncthreads();

  // ---------------- M + top-25 (value desc, index asc), fused on wave 0 ----------------
  if (tid < 64) {
    const float* P0 = Pp;
    const float* P1 = Pp + 1600;
    float mx = -INFINITY, su = 0.f;
#pragma unroll
    for (int s = 0; s < 25; ++s) {
      float vsum = P0[s * 64 + tid] + P1[s * 64 + tid];  // l 0..63 then 64..127
      mx = fmaxf(mx, vsum);
      su += vsum;
    }
    float v = mx - su * (1.0f / 128.0f);  // Lk = 128
    for (int it = 0; it < 25; ++it) {
      float bv2 = v;
      int bi = tid;
#pragma unroll
      for (int off = 32; off > 0; off >>= 1) {
        float ov = __shfl_xor(bv2, off);
        int oi = __shfl_xor(bi, off);
        if (ov > bv2 || (ov == bv2 && oi < bi)) { bv2 = ov; bi = oi; }
      }
      if (tid == 0) mtop[it] = bi;
      if (tid == bi) v = -INFINITY;
    }
  }
  __syncthreads();

  // ---------------- dense scores: broadcast form, 4 waves, lane=n ----------------
  float* sc = U;  // 25*68 floats (kT dead after qk)
  if (tid < 256) {
    const int w = tid >> 6, n = tid & 63;
    const float scale = 0.08838834764831845f;
    int rows[7];
#pragma unroll
    for (int t2 = 0; t2 < 7; ++t2) {
      int u = w + 4 * t2;
      rows[t2] = (u < 25) ? mtop[u] : 0;
    }
    float acc[7] = {0.f, 0.f, 0.f, 0.f, 0.f, 0.f, 0.f};
    for (int hq2 = 0; hq2 < 32; ++hq2) {
      float4 kv = fk4[n * FSQ + hq2];
#pragma unroll
      for (int t2 = 0; t2 < 7; ++t2) {
        int u = w + 4 * t2;
        if (u < 25) {
          float4 qv = fq4[rows[t2] * FSQ + hq2];
          acc[t2] = fmaf(qv.x, kv.x, acc[t2]);
          acc[t2] = fmaf(qv.y, kv.y, acc[t2]);
          acc[t2] = fmaf(qv.z, kv.z, acc[t2]);
          acc[t2] = fmaf(qv.w, kv.w, acc[t2]);
        }
      }
    }
#pragma unroll
    for (int t2 = 0; t2 < 7; ++t2) {
      int u = w + 4 * t2;
      if (u < 25) sc[u * AS + n] = acc[t2] * scale;
    }
  }
  __syncthreads();

  // ---------------- softmax over n (16 lanes per selected row) ----------------
  if (tid < 400) {
    int u = tid >> 4, g = tid & 15;
    float4* s4 = (float4*)(sc + u * AS);
    float4 v = s4[g];
    float mx = fmaxf(fmaxf(v.x, v.y), fmaxf(v.z, v.w));
    for (int off = 8; off; off >>= 1) mx = fmaxf(mx, __shfl_xor(mx, off));
    float4 e;
    e.x = __expf(v.x - mx); e.y = __expf(v.y - mx);
    e.z = __expf(v.z - mx); e.w = __expf(v.w - mx);
    float su = e.x + e.y + e.z + e.w;
    for (int off = 8; off; off >>= 1) su += __shfl_xor(su, off);
    float inv = 1.0f / su;
    e.x *= inv; e.y *= inv; e.z *= inv; e.w *= inv;
    s4[g] = e;
  }
  __syncthreads();

  // ---------------- upd rows: out[mtop[u]] = gamma*(attn@values) + x (2u x 4h) ----------------
  if (tid < 416) {
    int up = tid >> 5, hq = tid & 31;
    int u0 = up * 2, u1 = u0 + 1;
    bool has1 = (u1 < 25);
    int r0 = mtop[u0];
    int r1 = has1 ? mtop[u1] : 0;
    float4 a0 = make_float4(0.f, 0.f, 0.f, 0.f);
    float4 a1 = make_float4(0.f, 0.f, 0.f, 0.f);
    for (int n = 0; n < 64; ++n) {
      float4 vv = fv4[n * FSQ + hq];
      fma4(a0, sc[u0 * AS + n], vv);
      if (has1) fma4(a1, sc[u1 * AS + n], vv);
    }
    const float4* xg = (const float4*)xb;
    float4* og = (float4*)outb;
    float4 xr = xg[r0 * 32 + hq];
    og[r0 * 32 + hq] = make_float4(fmaf(gamma, a0.x, xr.x), fmaf(gamma, a0.y, xr.y),
                                   fmaf(gamma, a0.z, xr.z), fmaf(gamma, a0.w, xr.w));
    if (has1) {
      float4 xr1 = xg[r1 * 32 + hq];
      og[r1 * 32 + hq] = make_float4(fmaf(gamma, a1.x, xr1.x), fmaf(gamma, a1.y, xr1.y),
                                     fmaf(gamma, a1.z, xr1.z), fmaf(gamma, a1.w, xr1.w));
    }
  }
}

extern "C" void kernel_launch(void* const* d_in, const int* in_sizes, int n_in,
                              void* d_out, int out_size, void* d_ws, size_t ws_size,
                              hipStream_t stream) {
  const float* x   = (const float*)d_in[0];
  const float* wq  = (const float*)d_in[1];
  const float* bq  = (const float*)d_in[2];
  const float* wk  = (const float*)d_in[3];
  const float* bk  = (const float*)d_in[4];
  const float* wv  = (const float*)d_in[5];
  const float* bv  = (const float*)d_in[6];
  const float* gw1 = (const float*)d_in[7];
  const float* gb1 = (const float*)d_in[8];
  const float* gw2 = (const float*)d_in[9];
  const float* gb2 = (const float*)d_in[10];
  const float* gm  = (const float*)d_in[11];
  const int* idx   = (const int*)d_in[12];
  float* out = (float*)d_out;
  int B = in_sizes[0] / (64 * 128);
  hipLaunchKernelGGL(gcn_ssa_kernel, dim3(B), dim3(T), 0, stream,
                     x, wq, bq, wk, bk, wv, bv, gw1, gb1, gw2, gb2, gm, idx, out);
}

// Round 7
// 303.333 us; speedup vs baseline: 1.7762x; 1.1040x over previous
//
#include <hip/hip_runtime.h>
#include <math.h>

#define T 1024
#define FS 132   // feature row stride (floats)
#define FSQ 33   // in float4
#define AS 68    // adj/score row stride
#define ASQ 17

typedef __attribute__((ext_vector_type(8)))  short short8;
typedef __attribute__((ext_vector_type(4)))  float f32x4;
typedef __attribute__((ext_vector_type(16))) float f32x16;

__device__ __forceinline__ void macc(float& acc, const float4 a, const float4 b) {
  acc = fmaf(a.x, b.x, acc);
  acc = fmaf(a.y, b.y, acc);
  acc = fmaf(a.z, b.z, acc);
  acc = fmaf(a.w, b.w, acc);
}
__device__ __forceinline__ void fma4(float4& a, float s, const float4 b) {
  a.x = fmaf(s, b.x, a.x);
  a.y = fmaf(s, b.y, a.y);
  a.z = fmaf(s, b.z, a.z);
  a.w = fmaf(s, b.w, a.w);
}
__device__ __forceinline__ unsigned bf16rne(float f) {
  unsigned u = __float_as_uint(f);
  return (u + 0x7FFFu + ((u >> 16) & 1u)) >> 16;
}
// exact 3-way split: x = h + m + l (up to ~2^-33 tail), each bf16
__device__ __forceinline__ void split3(float4 a, float4 b, short8& vh, short8& vm, short8& vl) {
  const float xs[8] = {a.x, a.y, a.z, a.w, b.x, b.y, b.z, b.w};
#pragma unroll
  for (int e = 0; e < 8; ++e) {
    float x = xs[e];
    unsigned h = bf16rne(x);
    float r1 = x - __uint_as_float(h << 16);   // exact
    unsigned m = bf16rne(r1);
    float r2 = r1 - __uint_as_float(m << 16);  // exact
    unsigned l2 = bf16rne(r2);
    vh[e] = (short)h; vm[e] = (short)m; vl[e] = (short)l2;
  }
}
__device__ __forceinline__ void split2(float4 a, float4 b, short8& vh, short8& vl) {
  const float xs[8] = {a.x, a.y, a.z, a.w, b.x, b.y, b.z, b.w};
#pragma unroll
  for (int e = 0; e < 8; ++e) {
    float x = xs[e];
    unsigned h = bf16rne(x);
    float r1 = x - __uint_as_float(h << 16);
    unsigned l2 = bf16rne(r1);
    vh[e] = (short)h; vl[e] = (short)l2;
  }
}
__device__ __forceinline__ f32x16 mm32(short8 a, short8 b, f32x16 c) {
  return __builtin_amdgcn_mfma_f32_32x32x16_bf16(a, b, c, 0, 0, 0);
}
__device__ __forceinline__ f32x4 mm16(short8 a, short8 b, f32x4 c) {
  return __builtin_amdgcn_mfma_f32_16x16x32_bf16(a, b, c, 0, 0, 0);
}

__global__ __launch_bounds__(T) void gcn_ssa_kernel(
    const float* __restrict__ x,
    const float* __restrict__ wq, const float* __restrict__ bq,
    const float* __restrict__ wk, const float* __restrict__ bk,
    const float* __restrict__ wv, const float* __restrict__ bv,
    const float* __restrict__ gw1, const float* __restrict__ gb1,
    const float* __restrict__ gw2, const float* __restrict__ gb2,
    const float* __restrict__ gammap, const int* __restrict__ idxg,
    float* __restrict__ out)
{
  const int b = blockIdx.x, tid = threadIdx.x;
  const int l = tid & 63;
  const float* xb = x + (size_t)b * 8192;
  float* outb = out + (size_t)b * 8192;

  __shared__ __align__(16) float fq[64 * FS];
  __shared__ __align__(16) float fk[64 * FS];
  __shared__ __align__(16) float fv[64 * FS];
  __shared__ __align__(16) float U[12480];
  __shared__ __align__(16) float gw1T[8 * FS];
  __shared__ __align__(16) float gw2s[8 * 128];
  __shared__ __align__(16) float gb1s[8];
  __shared__ __align__(16) float gb2s[128];
  __shared__ float rinv_s[64], nrm_s[64], rinv2_s[64];
  __shared__ int mte[32];

  float4* fq4 = (float4*)fq;
  float4* fk4 = (float4*)fk;
  float4* fv4 = (float4*)fv;
  float4* U4 = (float4*)U;

  // ---------------- Stage A0: stage x (into fv, stride FS) + weights ----------------
  {
    const float4* xg = (const float4*)xb;
    for (int i = tid; i < 2048; i += T) {
      int r = i >> 5, cq = i & 31;
      fv4[r * FSQ + cq] = xg[i];
    }
    const float4* wqg = (const float4*)wq;
    const float4* wkg = (const float4*)wk;
    const float4* wvg = (const float4*)wv;
    for (int i = tid; i < 1024; i += T) {
      U4[i] = wqg[i];
      U4[1024 + i] = wkg[i];
      U4[2048 + i] = wvg[i];
    }
    if (tid < 64) {
      U[12288 + tid] = bq[tid];
      U[12352 + tid] = bk[tid];
      U[12416 + tid] = bv[tid];
    }
    for (int i = tid; i < 1024; i += T) {
      int h = i >> 3, j = i & 7;
      gw1T[j * FS + h] = gw1[i];
      gw2s[i] = gw2[i];
    }
    if (tid < 8) gb1s[tid] = gb1[tid];
    if (tid < 128) gb2s[tid] = gb2[tid];
  }
  __syncthreads();

  // ---------------- Stage A1: projection q,k,v (verbatim R5) ----------------
  float4 vacc0, vacc1;
  {
    const int o0 = (tid >> 5) << 1;
    const int hq = tid & 31;
    const float4* wqs = U4;
    const float4* wks = U4 + 1024;
    const float4* wvs = U4 + 2048;
    float4 aq0, aq1, ak0, ak1, av0, av1;
    {
      float bq0 = U[12288 + o0], bq1 = U[12288 + o0 + 1];
      float bk0 = U[12352 + o0], bk1 = U[12352 + o0 + 1];
      float bv0 = U[12416 + o0], bv1 = U[12416 + o0 + 1];
      aq0 = make_float4(bq0, bq0, bq0, bq0); aq1 = make_float4(bq1, bq1, bq1, bq1);
      ak0 = make_float4(bk0, bk0, bk0, bk0); ak1 = make_float4(bk1, bk1, bk1, bk1);
      av0 = make_float4(bv0, bv0, bv0, bv0); av1 = make_float4(bv1, bv1, bv1, bv1);
    }
    for (int cq = 0; cq < 16; ++cq) {
      float4 x0 = fv4[(4 * cq + 0) * FSQ + hq];
      float4 x1 = fv4[(4 * cq + 1) * FSQ + hq];
      float4 x2 = fv4[(4 * cq + 2) * FSQ + hq];
      float4 x3 = fv4[(4 * cq + 3) * FSQ + hq];
      float4 w;
      w = wqs[o0 * 16 + cq];       fma4(aq0, w.x, x0); fma4(aq0, w.y, x1); fma4(aq0, w.z, x2); fma4(aq0, w.w, x3);
      w = wqs[(o0 + 1) * 16 + cq]; fma4(aq1, w.x, x0); fma4(aq1, w.y, x1); fma4(aq1, w.z, x2); fma4(aq1, w.w, x3);
      w = wks[o0 * 16 + cq];       fma4(ak0, w.x, x0); fma4(ak0, w.y, x1); fma4(ak0, w.z, x2); fma4(ak0, w.w, x3);
      w = wks[(o0 + 1) * 16 + cq]; fma4(ak1, w.x, x0); fma4(ak1, w.y, x1); fma4(ak1, w.z, x2); fma4(ak1, w.w, x3);
      w = wvs[o0 * 16 + cq];       fma4(av0, w.x, x0); fma4(av0, w.y, x1); fma4(av0, w.z, x2); fma4(av0, w.w, x3);
      w = wvs[(o0 + 1) * 16 + cq]; fma4(av1, w.x, x0); fma4(av1, w.y, x1); fma4(av1, w.z, x2); fma4(av1, w.w, x3);
    }
    fq4[o0 * FSQ + hq] = aq0;
    fq4[(o0 + 1) * FSQ + hq] = aq1;
    fk4[o0 * FSQ + hq] = ak0;
    fk4[(o0 + 1) * FSQ + hq] = ak1;
    vacc0 = av0; vacc1 = av1;
  }
  __syncthreads();
  {
    const int o0 = (tid >> 5) << 1, hq = tid & 31;
    fv4[o0 * FSQ + hq] = vacc0;
    fv4[(o0 + 1) * FSQ + hq] = vacc1;
  }
  __syncthreads();

  float* adjb = U;           // 64*68
  float* t1T = U + 4352;     // 8*68
  float* hT  = U + 4896;     // 8*68
  float* gsm = U + 5440;     // 64*8
  float4* adj4 = (float4*)adjb;

  // ---------------- Stage B: three GCN branches ----------------
  for (int brr = 0; brr < 3; ++brr) {
    float* f = (brr == 0) ? fq : (brr == 1) ? fk : fv;
    float4* f4 = (float4*)f;

    // phase1: row sum + sumsq (verbatim R5)
    {
      int row = tid >> 4, g = tid & 15;
      float4 aa = f4[row * FSQ + 2 * g];
      float4 c = f4[row * FSQ + 2 * g + 1];
      float s0 = aa.x + aa.y + aa.z + aa.w + c.x + c.y + c.z + c.w;
      float s1 = aa.x * aa.x + aa.y * aa.y + aa.z * aa.z + aa.w * aa.w +
                 c.x * c.x + c.y * c.y + c.z * c.z + c.w * c.w;
      for (int off = 8; off; off >>= 1) {
        s0 += __shfl_xor(s0, off);
        s1 += __shfl_xor(s1, off);
      }
      if (g == 0) {
        rinv_s[row] = (s0 == 0.0f) ? 0.0f : (1.0f / s0);
        nrm_s[row] = 1.0f / fmaxf(sqrtf(s1), 1e-8f);
      }
    }
    __syncthreads();

    // phase2: gram via MFMA 6-term 3-way split (waves 0-3) || t1 vector (512-767)
    if (tid < 256) {
      const int w = tid >> 6;            // tile: rows (w>>1)*32, cols (w&1)*32
      const int r0 = (w >> 1) * 32, c0 = (w & 1) * 32;
      const int lr = l & 31;
      const int kg = (l >> 5) * 4;       // layout (ii): e<4 -> k=kg+e ; e>=4 -> k=8+kg+(e-4)
      f32x16 acc = (f32x16)0.f;
      for (int ks = 0; ks < 8; ++ks) {
        int kb = ks * 16;
        float4 a0 = *(const float4*)(f + (r0 + lr) * FS + kb + kg);
        float4 a1 = *(const float4*)(f + (r0 + lr) * FS + kb + 8 + kg);
        float4 b0 = *(const float4*)(f + (c0 + lr) * FS + kb + kg);
        float4 b1 = *(const float4*)(f + (c0 + lr) * FS + kb + 8 + kg);
        short8 ah, am, al2, bh, bm, bl;
        split3(a0, a1, ah, am, al2);
        split3(b0, b1, bh, bm, bl);
        acc = mm32(ah, bh, acc);
        acc = mm32(ah, bm, acc);
        acc = mm32(am, bh, acc);
        acc = mm32(ah, bl, acc);
        acc = mm32(al2, bh, acc);
        acc = mm32(am, bm, acc);
      }
      float nm = nrm_s[c0 + lr];
#pragma unroll
      for (int reg = 0; reg < 16; ++reg) {
        int r = r0 + (reg & 3) + 8 * (reg >> 2) + 4 * (l >> 5);
        int m = c0 + lr;
        float sim = acc[reg] * nrm_s[r] * nm;
        float aa = (sim > 0.5f) ? 1.0f : 0.0f;
        if (r == m) aa += 1.0f;
        adjb[r * AS + m] = aa;
      }
    } else if (tid >= 512 && tid < 768) {
      int lt = tid - 512;
      int n = lt >> 2, j0 = (lt & 3) * 2;
      float a0 = 0.f, a1 = 0.f;
      const float4* w0 = (const float4*)(gw1T + j0 * FS);
      const float4* w1 = (const float4*)(gw1T + (j0 + 1) * FS);
      for (int hc = 0; hc < 32; ++hc) {
        float4 fx = f4[n * FSQ + hc];
        macc(a0, fx, w0[hc]);
        macc(a1, fx, w1[hc]);
      }
      float rv = rinv_s[n];
      t1T[j0 * AS + n] = a0 * rv;
      t1T[(j0 + 1) * AS + n] = a1 * rv;
    }
    __syncthreads();

    // phase3: adjacency row sums (verbatim R5)
    {
      int row = tid >> 4, g = tid & 15;
      float4 aa = adj4[row * ASQ + g];
      float s = aa.x + aa.y + aa.z + aa.w;
      for (int off = 8; off; off >>= 1) s += __shfl_xor(s, off);
      if (g == 0) rinv2_s[row] = 1.0f / s;
    }
    __syncthreads();

    // phase4: h = relu(rinv2*(adj@t1) + gb1) (verbatim R5)
    if (tid < 512) {
      int n = tid >> 3, j = tid & 7;
      float acc = 0.f;
      const float4* a4 = (const float4*)(adjb + n * AS);
      const float4* t4 = (const float4*)(t1T + j * AS);
      for (int mq = 0; mq < 16; ++mq) macc(acc, a4[mq], t4[mq]);
      hT[j * AS + n] = fmaxf(acc * rinv2_s[n] + gb1s[j], 0.0f);
    }
    __syncthreads();

    // phase5: g = rinv2*(adj@h) (verbatim R5)
    if (tid < 512) {
      int n = tid >> 3, j = tid & 7;
      float acc = 0.f;
      const float4* a4 = (const float4*)(adjb + n * AS);
      const float4* h4 = (const float4*)(hT + j * AS);
      for (int mq = 0; mq < 16; ++mq) macc(acc, a4[mq], h4[mq]);
      gsm[n * 8 + j] = acc * rinv2_s[n];
    }
    __syncthreads();

    // phase6: f = g @ gw2 + gb2 (verbatim R5)
    {
      int n0 = tid >> 5, hq = tid & 31;
      int n1 = n0 + 32;
      const float4* g4 = (const float4*)gsm;
      float4 ga0 = g4[n0 * 2], ga1 = g4[n0 * 2 + 1];
      float4 gc0 = g4[n1 * 2], gc1 = g4[n1 * 2 + 1];
      const float* pa0 = (const float*)&ga0;
      const float* pa1 = (const float*)&ga1;
      const float* pc0 = (const float*)&gc0;
      const float* pc1 = (const float*)&gc1;
      const float4* w4 = (const float4*)gw2s;
      float4 bquad = ((const float4*)gb2s)[hq];
      float4 acc0 = bquad, acc1 = bquad;
#pragma unroll
      for (int j = 0; j < 4; ++j) {
        float4 w = w4[j * 32 + hq];
        fma4(acc0, pa0[j], w);
        fma4(acc1, pc0[j], w);
      }
#pragma unroll
      for (int j = 0; j < 4; ++j) {
        float4 w = w4[(j + 4) * 32 + hq];
        fma4(acc0, pa1[j], w);
        fma4(acc1, pc1[j], w);
      }
      f4[n0 * FSQ + hq] = acc0;
      f4[n1 * FSQ + hq] = acc1;
    }
    __syncthreads();
  }

  // ---------------- kT build (verbatim R5) ----------------
  float* kT = U;             // 128*68
  float* Pp = U + 8704;      // 2 x 25 x 64
  {
    const int c = tid >> 6;
    const int n = tid & 63;
    float4 v0 = fk4[n * FSQ + 2 * c];
    float4 v1 = fk4[n * FSQ + 2 * c + 1];
    const float* p0 = (const float*)&v0;
    const float* p1 = (const float*)&v1;
#pragma unroll
    for (int e = 0; e < 4; ++e) kT[(8 * c + e) * AS + n] = p0[e];
#pragma unroll
    for (int e = 0; e < 4; ++e) kT[(8 * c + 4 + e) * AS + n] = p1[e];
  }
  __syncthreads();

  // ---------------- qk_sample (0-127) || cumsum all rows (128-255) (verbatim R5) ----------------
  const float gamma = *gammap;
  if (tid < 128) {
    const int w = tid >> 6, n = l;
    float acc[25];
#pragma unroll
    for (int s = 0; s < 25; ++s) acc[s] = 0.f;
    const float* qrow = fq + n * FS + w * 64;
    for (int lb = 0; lb < 16; ++lb) {
      float4 qv = *(const float4*)(qrow + 4 * lb);
      const float* qp = (const float*)&qv;
#pragma unroll
      for (int i = 0; i < 4; ++i) {
        const float qs = qp[i];
        const int base = __builtin_amdgcn_readfirstlane((w * 64 + 4 * lb + i) * 25);
#pragma unroll
        for (int s = 0; s < 25; ++s) {
          acc[s] = fmaf(qs, kT[idxg[base + s] * AS + n], acc[s]);
        }
      }
    }
    float* P = Pp + w * 1600;
#pragma unroll
    for (int s = 0; s < 25; ++s) P[s * 64 + n] = acc[s];
  } else if (tid < 256) {
    const int h = tid - 128;
    float acc = 0.f;
    for (int n = 0; n < 64; ++n) {
      acc += fv[n * FS + h];
      outb[n * 128 + h] = fmaf(gamma, acc, xb[n * 128 + h]);
    }
  }
  __syncthreads();

  // ---------------- M + top-25 (value desc, index asc) on wave 0 ----------------
  if (tid < 64) {
    if (tid >= 25 && tid < 32) mte[tid] = 0;
    const float* P0 = Pp;
    const float* P1 = Pp + 1600;
    float mx = -INFINITY, su = 0.f;
#pragma unroll
    for (int s = 0; s < 25; ++s) {
      float vsum = P0[s * 64 + tid] + P1[s * 64 + tid];
      mx = fmaxf(mx, vsum);
      su += vsum;
    }
    float v = mx - su * (1.0f / 128.0f);
    for (int it = 0; it < 25; ++it) {
      float bv2 = v;
      int bi = tid;
#pragma unroll
      for (int off = 32; off > 0; off >>= 1) {
        float ov = __shfl_xor(bv2, off);
        int oi = __shfl_xor(bi, off);
        if (ov > bv2 || (ov == bv2 && oi < bi)) { bv2 = ov; bi = oi; }
      }
      if (tid == 0) mte[it] = bi;
      if (tid == bi) v = -INFINITY;
    }
  }
  __syncthreads();

  // ---------------- dense scores MFMA (waves 0-1) || vT build (128-1023) ----------------
  float* sc = U + 8704;      // 25*68 (Pp dead)
  float* vT = U;             // 128*68 (kT dead)
  if (tid < 128) {
    const int w = tid >> 6;            // col-tile n0 = w*32
    const int lr = l & 31;
    const int kg = (l >> 5) * 4;
    const int qr = mte[lr];
    const float scale = 0.08838834764831845f;
    f32x16 acc = (f32x16)0.f;
    for (int ks = 0; ks < 8; ++ks) {
      int kb = ks * 16;
      float4 a0 = *(const float4*)(fq + qr * FS + kb + kg);
      float4 a1 = *(const float4*)(fq + qr * FS + kb + 8 + kg);
      float4 b0 = *(const float4*)(fk + (w * 32 + lr) * FS + kb + kg);
      float4 b1 = *(const float4*)(fk + (w * 32 + lr) * FS + kb + 8 + kg);
      short8 ah, al2, bh, bl;
      split2(a0, a1, ah, al2);
      split2(b0, b1, bh, bl);
      acc = mm32(ah, bh, acc);
      acc = mm32(ah, bl, acc);
      acc = mm32(al2, bh, acc);
    }
#pragma unroll
    for (int reg = 0; reg < 16; ++reg) {
      int uu = (reg & 3) + 8 * (reg >> 2) + 4 * (l >> 5);
      if (uu < 25) sc[uu * AS + w * 32 + lr] = acc[reg] * scale;
    }
  } else {
    for (int i = tid - 128; i < 8192; i += 896) {
      int h2 = i >> 6, n = i & 63;
      vT[h2 * AS + n] = fv[n * FS + h2];
    }
  }
  __syncthreads();

  // ---------------- softmax over n (verbatim R5, sc rebased) ----------------
  if (tid < 400) {
    int u = tid >> 4, g = tid & 15;
    float4* s4 = (float4*)(sc + u * AS);
    float4 v = s4[g];
    float mx = fmaxf(fmaxf(v.x, v.y), fmaxf(v.z, v.w));
    for (int off = 8; off; off >>= 1) mx = fmaxf(mx, __shfl_xor(mx, off));
    float4 e;
    e.x = __expf(v.x - mx); e.y = __expf(v.y - mx);
    e.z = __expf(v.z - mx); e.w = __expf(v.w - mx);
    float su = e.x + e.y + e.z + e.w;
    for (int off = 8; off; off >>= 1) su += __shfl_xor(su, off);
    float inv = 1.0f / su;
    e.x *= inv; e.y *= inv; e.z *= inv; e.w *= inv;
    s4[g] = e;
  }
  __syncthreads();

  // ---------------- upd MFMA: out[mte[u]] = gamma*(attn@v) + x ----------------
  if (tid < 512) {
    const int w = tid >> 6;            // 0..7
    const int li = l & 15;
    const int kg4 = (l >> 4) * 4;      // layout (ii) for 16x16x32
#pragma unroll
    for (int i = 0; i < 2; ++i) {
      int t = w * 2 + i;
      int ut = t >> 3, ht = t & 7;
      int u = ut * 16 + li;            // A row (rows >=25 are garbage, discarded)
      f32x4 acc = (f32x4)0.f;
#pragma unroll
      for (int ks = 0; ks < 2; ++ks) {
        int kb = ks * 32;
        float4 a0 = *(const float4*)(sc + u * AS + kb + kg4);
        float4 a1 = *(const float4*)(sc + u * AS + kb + 16 + kg4);
        float4 b0 = *(const float4*)(vT + (ht * 16 + li) * AS + kb + kg4);
        float4 b1 = *(const float4*)(vT + (ht * 16 + li) * AS + kb + 16 + kg4);
        short8 ah, al2, bh, bl;
        split2(a0, a1, ah, al2);
        split2(b0, b1, bh, bl);
        acc = mm16(ah, bh, acc);
        acc = mm16(ah, bl, acc);
        acc = mm16(al2, bh, acc);
      }
      int hcol = ht * 16 + li;
#pragma unroll
      for (int r = 0; r < 4; ++r) {
        int uu = ut * 16 + (l >> 4) * 4 + r;
        if (uu < 25) {
          int row = mte[uu];
          int o = row * 128 + hcol;
          outb[o] = fmaf(gamma, acc[r], xb[o]);
        }
      }
    }
  }
}

extern "C" void kernel_launch(void* const* d_in, const int* in_sizes, int n_in,
                              void* d_out, int out_size, void* d_ws, size_t ws_size,
                              hipStream_t stream) {
  const float* x   = (const float*)d_in[0];
  const float* wq  = (const float*)d_in[1];
  const float* bq  = (const float*)d_in[2];
  const float* wk  = (const float*)d_in[3];
  const float* bk  = (const float*)d_in[4];
  const float* wv  = (const float*)d_in[5];
  const float* bv  = (const float*)d_in[6];
  const float* gw1 = (const float*)d_in[7];
  const float* gb1 = (const float*)d_in[8];
  const float* gw2 = (const float*)d_in[9];
  const float* gb2 = (const float*)d_in[10];
  const float* gm  = (const float*)d_in[11];
  const int* idx   = (const int*)d_in[12];
  float* out = (float*)d_out;
  int B = in_sizes[0] / (64 * 128);
  hipLaunchKernelGGL(gcn_ssa_kernel, dim3(B), dim3(T), 0, stream,
                     x, wq, bq, wk, bk, wv, bv, gw1, gb1, gw2, gb2, gm, idx, out);
}

// Round 8
// 296.559 us; speedup vs baseline: 1.8168x; 1.0228x over previous
//
#include <hip/hip_runtime.h>
#include <math.h>

#define T 1024
#define FS 132   // feature row stride (floats)
#define FSQ 33   // in float4
#define AS 68    // scratch row stride

typedef __attribute__((ext_vector_type(8)))  short short8;
typedef __attribute__((ext_vector_type(4)))  float f32x4;
typedef __attribute__((ext_vector_type(16))) float f32x16;
typedef __attribute__((ext_vector_type(4)))  unsigned u32x4;
typedef __attribute__((ext_vector_type(2)))  unsigned u32x2;

__device__ __forceinline__ void fma4(float4& a, float s, const float4 b) {
  a.x = fmaf(s, b.x, a.x);
  a.y = fmaf(s, b.y, a.y);
  a.z = fmaf(s, b.z, a.z);
  a.w = fmaf(s, b.w, a.w);
}
__device__ __forceinline__ unsigned bf16rne(float f) {
  unsigned u = __float_as_uint(f);
  return (u + 0x7FFFu + ((u >> 16) & 1u)) >> 16;
}
__device__ __forceinline__ void split3(float4 a, float4 b, short8& vh, short8& vm, short8& vl) {
  const float xs[8] = {a.x, a.y, a.z, a.w, b.x, b.y, b.z, b.w};
#pragma unroll
  for (int e = 0; e < 8; ++e) {
    float x = xs[e];
    unsigned h = bf16rne(x);
    float r1 = x - __uint_as_float(h << 16);
    unsigned m = bf16rne(r1);
    float r2 = r1 - __uint_as_float(m << 16);
    unsigned l2 = bf16rne(r2);
    vh[e] = (short)h; vm[e] = (short)m; vl[e] = (short)l2;
  }
}
__device__ __forceinline__ void split2(float4 a, float4 b, short8& vh, short8& vl) {
  const float xs[8] = {a.x, a.y, a.z, a.w, b.x, b.y, b.z, b.w};
#pragma unroll
  for (int e = 0; e < 8; ++e) {
    float x = xs[e];
    unsigned h = bf16rne(x);
    float r1 = x - __uint_as_float(h << 16);
    unsigned l2 = bf16rne(r1);
    vh[e] = (short)h; vl[e] = (short)l2;
  }
}
__device__ __forceinline__ f32x16 mm32(short8 a, short8 b, f32x16 c) {
  return __builtin_amdgcn_mfma_f32_32x32x16_bf16(a, b, c, 0, 0, 0);
}
__device__ __forceinline__ f32x4 mm16(short8 a, short8 b, f32x4 c) {
  return __builtin_amdgcn_mfma_f32_16x16x32_bf16(a, b, c, 0, 0, 0);
}

__global__ __launch_bounds__(T) void gcn_ssa_kernel(
    const float* __restrict__ x,
    const float* __restrict__ wq, const float* __restrict__ bq,
    const float* __restrict__ wk, const float* __restrict__ bk,
    const float* __restrict__ wv, const float* __restrict__ bv,
    const float* __restrict__ gw1, const float* __restrict__ gb1,
    const float* __restrict__ gw2, const float* __restrict__ gb2,
    const float* __restrict__ gammap, const int* __restrict__ idxg,
    float* __restrict__ out)
{
  const int b = blockIdx.x, tid = threadIdx.x;
  const int l = tid & 63;
  const int wid = tid >> 6;
  const float* xb = x + (size_t)b * 8192;
  float* outb = out + (size_t)b * 8192;

  __shared__ __align__(16) float fq[64 * FS];
  __shared__ __align__(16) float fk[64 * FS];
  __shared__ __align__(16) float fv[64 * FS];
  __shared__ __align__(16) float U[11904];     // xT+bias | adjB/t1T/hT/gsm | kT/Pp/sc/vT
  __shared__ __align__(16) float gw1T[16 * FS]; // rows 8-15 zero
  __shared__ __align__(16) float gb1s[8];
  __shared__ __align__(16) float gb2s[128];
  __shared__ float rinv_s[3][64], nrm_s[3][64], rinv2_s[3][64];
  __shared__ int mte[32];

  float4* fq4 = (float4*)fq;
  float4* fk4 = (float4*)fk;
  float4* fv4 = (float4*)fv;

  // ---------------- A0: stage xT (stride 68, conflict-free), biases, gw1T ----------------
  {
    const float4* xg = (const float4*)xb;
    for (int i = tid; i < 2048; i += T) {
      int c = i & 63, hq = i >> 6;      // lanes: c consecutive -> LDS banks spread
      float4 v = xg[c * 32 + hq];
      int h = hq * 4;
      U[(h + 0) * AS + c] = v.x;
      U[(h + 1) * AS + c] = v.y;
      U[(h + 2) * AS + c] = v.z;
      U[(h + 3) * AS + c] = v.w;
    }
    if (tid < 192) U[8704 + tid] = (tid < 64) ? bq[tid] : (tid < 128) ? bk[tid - 64] : bv[tid - 128];
    for (int i = tid; i < 2048; i += T) {
      int j = i >> 7, h = i & 127;
      gw1T[j * FS + h] = (j < 8) ? gw1[h * 8 + j] : 0.f;
    }
    if (tid < 8) gb1s[tid] = gb1[tid];
    if (tid < 128) gb2s[tid] = gb2[tid];
  }
  __syncthreads();

  // ---------------- A1: all 3 projections via MFMA 6-term (12 waves) ----------------
  if (wid < 12) {
    const int p = wid >> 2, strip = wid & 3;
    const float* wsel = (p == 0) ? wq : (p == 1) ? wk : wv;
    float* fdst = (p == 0) ? fq : (p == 1) ? fk : fv;
    const int lr = l & 31, kg = (l >> 5) * 4;
    const int h = strip * 32 + lr;
    f32x16 acc0 = (f32x16)0.f, acc1 = (f32x16)0.f;
    for (int ks = 0; ks < 4; ++ks) {
      int kb = ks * 16;
      float4 b0 = *(const float4*)(U + h * AS + kb + kg);
      float4 b1 = *(const float4*)(U + h * AS + kb + 8 + kg);
      short8 bh, bm, bl;
      split3(b0, b1, bh, bm, bl);
      float4 a0 = *(const float4*)(wsel + lr * 64 + kb + kg);
      float4 a1 = *(const float4*)(wsel + lr * 64 + kb + 8 + kg);
      short8 ah, am, al;
      split3(a0, a1, ah, am, al);
      acc0 = mm32(ah, bh, acc0); acc0 = mm32(ah, bm, acc0); acc0 = mm32(am, bh, acc0);
      acc0 = mm32(ah, bl, acc0); acc0 = mm32(al, bh, acc0); acc0 = mm32(am, bm, acc0);
      a0 = *(const float4*)(wsel + (32 + lr) * 64 + kb + kg);
      a1 = *(const float4*)(wsel + (32 + lr) * 64 + kb + 8 + kg);
      split3(a0, a1, ah, am, al);
      acc1 = mm32(ah, bh, acc1); acc1 = mm32(ah, bm, acc1); acc1 = mm32(am, bh, acc1);
      acc1 = mm32(ah, bl, acc1); acc1 = mm32(al, bh, acc1); acc1 = mm32(am, bm, acc1);
    }
#pragma unroll
    for (int reg = 0; reg < 16; ++reg) {
      int ro = (reg & 3) + 8 * (reg >> 2) + 4 * (l >> 5);
      fdst[ro * FS + h] = acc0[reg] + U[8704 + p * 64 + ro];
      fdst[(32 + ro) * FS + h] = acc1[reg] + U[8704 + p * 64 + 32 + ro];
    }
  }
  __syncthreads();

  // ---------------- B1: row stats, all 3 branches ----------------
  {
    int row = tid >> 4, g = tid & 15;
#pragma unroll
    for (int br = 0; br < 3; ++br) {
      const float4* f4b = (br == 0) ? fq4 : (br == 1) ? fk4 : fv4;
      float4 aa = f4b[row * FSQ + 2 * g];
      float4 cc = f4b[row * FSQ + 2 * g + 1];
      float s0 = aa.x + aa.y + aa.z + aa.w + cc.x + cc.y + cc.z + cc.w;
      float s1 = aa.x * aa.x + aa.y * aa.y + aa.z * aa.z + aa.w * aa.w +
                 cc.x * cc.x + cc.y * cc.y + cc.z * cc.z + cc.w * cc.w;
      for (int off = 8; off; off >>= 1) {
        s0 += __shfl_xor(s0, off);
        s1 += __shfl_xor(s1, off);
      }
      if (g == 0) {
        rinv_s[br][row] = (s0 == 0.0f) ? 0.0f : (1.0f / s0);
        nrm_s[br][row] = 1.0f / fmaxf(sqrtf(s1), 1e-8f);
      }
    }
  }
  __syncthreads();

  unsigned short* adjw = (unsigned short*)U;   // [3][64][72] bf16 exact
  float* t1T = U + 6912;                       // [3*8][68]
  float* hT  = U + 8544;                       // [3*8][68]
  float* gsm = U + 10176;                      // [3*64][8]

  // ---------------- B2: grams (12 waves, 6-term) || t1 MFMA (4 waves, 6-term) ----------------
  if (wid < 12) {
    int br = wid >> 2, tile = wid & 3;
    const float* f = (br == 0) ? fq : (br == 1) ? fk : fv;
    int r0 = (tile >> 1) * 32, c0 = (tile & 1) * 32;
    int lr = l & 31, kg = (l >> 5) * 4;
    f32x16 acc = (f32x16)0.f;
    for (int ks = 0; ks < 8; ++ks) {
      int kb = ks * 16;
      float4 a0 = *(const float4*)(f + (r0 + lr) * FS + kb + kg);
      float4 a1 = *(const float4*)(f + (r0 + lr) * FS + kb + 8 + kg);
      float4 b0 = *(const float4*)(f + (c0 + lr) * FS + kb + kg);
      float4 b1 = *(const float4*)(f + (c0 + lr) * FS + kb + 8 + kg);
      short8 ah, am, al, bh, bm, bl;
      split3(a0, a1, ah, am, al);
      split3(b0, b1, bh, bm, bl);
      acc = mm32(ah, bh, acc); acc = mm32(ah, bm, acc); acc = mm32(am, bh, acc);
      acc = mm32(ah, bl, acc); acc = mm32(al, bh, acc); acc = mm32(am, bm, acc);
    }
    float nm = nrm_s[br][c0 + lr];
#pragma unroll
    for (int reg = 0; reg < 16; ++reg) {
      int rowg = r0 + (reg & 3) + 8 * (reg >> 2) + 4 * (l >> 5);
      int m = c0 + lr;
      float sim = acc[reg] * nrm_s[br][rowg] * nm;
      unsigned short e = (sim > 0.5f) ? (unsigned short)0x3F80 : (unsigned short)0;
      if (rowg == m) e = (sim > 0.5f) ? (unsigned short)0x4000 : (unsigned short)0x3F80;
      adjw[(br * 64 + rowg) * 72 + m] = e;
    }
  } else {
    int u = wid - 12;
    int j15 = l & 15, kg4 = (l >> 4) * 4;
    short8 gbh[4], gbm[4], gbl[4];
#pragma unroll
    for (int ks = 0; ks < 4; ++ks) {
      int kb = ks * 32;
      float4 b0 = *(const float4*)(gw1T + j15 * FS + kb + kg4);
      float4 b1 = *(const float4*)(gw1T + j15 * FS + kb + 16 + kg4);
      split3(b0, b1, gbh[ks], gbm[ks], gbl[ks]);
    }
#pragma unroll
    for (int i = 0; i < 3; ++i) {
      int tl = u * 3 + i;
      int br = tl >> 2, mt = tl & 3;
      const float* f = (br == 0) ? fq : (br == 1) ? fk : fv;
      f32x4 acc = (f32x4)0.f;
      for (int ks = 0; ks < 4; ++ks) {
        int kb = ks * 32;
        float4 a0 = *(const float4*)(f + (mt * 16 + j15) * FS + kb + kg4);
        float4 a1 = *(const float4*)(f + (mt * 16 + j15) * FS + kb + 16 + kg4);
        short8 ah, am, al;
        split3(a0, a1, ah, am, al);
        acc = mm16(ah, gbh[ks], acc); acc = mm16(ah, gbm[ks], acc); acc = mm16(am, gbh[ks], acc);
        acc = mm16(ah, gbl[ks], acc); acc = mm16(al, gbh[ks], acc); acc = mm16(am, gbm[ks], acc);
      }
      if (j15 < 8) {
#pragma unroll
        for (int r = 0; r < 4; ++r) {
          int n = mt * 16 + (l >> 4) * 4 + r;
          t1T[(br * 8 + j15) * AS + n] = acc[r] * rinv_s[br][n];
        }
      }
    }
  }
  __syncthreads();

  // ---------------- B3: adjacency row sums (exact bf16 unpack) ----------------
  if (tid < 768) {
    int rid = tid >> 2, g = tid & 3;
    int br = rid >> 6, n = rid & 63;
    const unsigned short* rp = adjw + (br * 64 + n) * 72 + g * 16;
    u32x4 v0 = *(const u32x4*)rp;
    u32x4 v1 = *(const u32x4*)(rp + 8);
    unsigned wds[8] = {v0.x, v0.y, v0.z, v0.w, v1.x, v1.y, v1.z, v1.w};
    float s = 0.f;
#pragma unroll
    for (int e = 0; e < 8; ++e) {
      s += __uint_as_float(wds[e] << 16);
      s += __uint_as_float(wds[e] & 0xFFFF0000u);
    }
    s += __shfl_xor(s, 1);
    s += __shfl_xor(s, 2);
    if (g == 0) rinv2_s[br][n] = 1.0f / s;
  }
  __syncthreads();

  // ---------------- B4: h = relu(rinv2*(adj@t1) + gb1) — adj exact, 3-term ----------------
  if (tid < 768) {
    int br = wid >> 2, mt = wid & 3;
    int j15 = l & 15, kg4 = (l >> 4) * 4;
    int arow = br * 64 + mt * 16 + j15;
    f32x4 acc = (f32x4)0.f;
#pragma unroll
    for (int ks = 0; ks < 2; ++ks) {
      int kb = ks * 32;
      u32x2 lo = *(const u32x2*)(adjw + arow * 72 + kb + kg4);
      u32x2 hi = *(const u32x2*)(adjw + arow * 72 + kb + 16 + kg4);
      u32x4 cc; cc.x = lo.x; cc.y = lo.y; cc.z = hi.x; cc.w = hi.y;
      short8 af = __builtin_bit_cast(short8, cc);
      float4 b0 = *(const float4*)(t1T + (br * 8 + j15) * AS + kb + kg4);
      float4 b1 = *(const float4*)(t1T + (br * 8 + j15) * AS + kb + 16 + kg4);
      short8 bh, bm, bl;
      split3(b0, b1, bh, bm, bl);
      acc = mm16(af, bh, acc); acc = mm16(af, bm, acc); acc = mm16(af, bl, acc);
    }
    if (j15 < 8) {
      float g1 = gb1s[j15];
#pragma unroll
      for (int r = 0; r < 4; ++r) {
        int n = mt * 16 + (l >> 4) * 4 + r;
        hT[(br * 8 + j15) * AS + n] = fmaxf(fmaf(acc[r], rinv2_s[br][n], g1), 0.0f);
      }
    }
  }
  __syncthreads();

  // ---------------- B5: g = rinv2*(adj@h) ----------------
  if (tid < 768) {
    int br = wid >> 2, mt = wid & 3;
    int j15 = l & 15, kg4 = (l >> 4) * 4;
    int arow = br * 64 + mt * 16 + j15;
    f32x4 acc = (f32x4)0.f;
#pragma unroll
    for (int ks = 0; ks < 2; ++ks) {
      int kb = ks * 32;
      u32x2 lo = *(const u32x2*)(adjw + arow * 72 + kb + kg4);
      u32x2 hi = *(const u32x2*)(adjw + arow * 72 + kb + 16 + kg4);
      u32x4 cc; cc.x = lo.x; cc.y = lo.y; cc.z = hi.x; cc.w = hi.y;
      short8 af = __builtin_bit_cast(short8, cc);
      float4 b0 = *(const float4*)(hT + (br * 8 + j15) * AS + kb + kg4);
      float4 b1 = *(const float4*)(hT + (br * 8 + j15) * AS + kb + 16 + kg4);
      short8 bh, bm, bl;
      split3(b0, b1, bh, bm, bl);
      acc = mm16(af, bh, acc); acc = mm16(af, bm, acc); acc = mm16(af, bl, acc);
    }
    if (j15 < 8) {
#pragma unroll
      for (int r = 0; r < 4; ++r) {
        int n = mt * 16 + (l >> 4) * 4 + r;
        gsm[(br * 64 + n) * 8 + j15] = acc[r] * rinv2_s[br][n];
      }
    }
  }
  __syncthreads();

  // ---------------- B6: f = g @ gw2 + gb2 (vector, gw2 from L2) ----------------
  {
    int n0 = tid >> 5, hq = tid & 31;
    float4 wreg[8];
#pragma unroll
    for (int j = 0; j < 8; ++j) wreg[j] = ((const float4*)gw2)[j * 32 + hq];
    float4 bquad = ((const float4*)gb2s)[hq];
#pragma unroll
    for (int br = 0; br < 3; ++br) {
      float4* f4b = (br == 0) ? fq4 : (br == 1) ? fk4 : fv4;
#pragma unroll
      for (int half = 0; half < 2; ++half) {
        int n = n0 + 32 * half;
        const float* g = gsm + (br * 64 + n) * 8;
        float4 g0 = *(const float4*)g;
        float4 g1 = *(const float4*)(g + 4);
        float4 a = bquad;
        fma4(a, g0.x, wreg[0]); fma4(a, g0.y, wreg[1]); fma4(a, g0.z, wreg[2]); fma4(a, g0.w, wreg[3]);
        fma4(a, g1.x, wreg[4]); fma4(a, g1.y, wreg[5]); fma4(a, g1.z, wreg[6]); fma4(a, g1.w, wreg[7]);
        f4b[n * FSQ + hq] = a;
      }
    }
  }
  __syncthreads();

  // ---------------- kT build (verbatim R7) ----------------
  float* kT = U;             // 128*68
  float* Pp = U + 8704;      // 2 x 25 x 64
  {
    const int c = tid >> 6;
    const int n = tid & 63;
    float4 v0 = fk4[n * FSQ + 2 * c];
    float4 v1 = fk4[n * FSQ + 2 * c + 1];
    const float* p0 = (const float*)&v0;
    const float* p1 = (const float*)&v1;
#pragma unroll
    for (int e = 0; e < 4; ++e) kT[(8 * c + e) * AS + n] = p0[e];
#pragma unroll
    for (int e = 0; e < 4; ++e) kT[(8 * c + 4 + e) * AS + n] = p1[e];
  }
  __syncthreads();

  // ---------------- qk_sample (0-127) || cumsum all rows (128-255) ----------------
  const float gamma = *gammap;
  if (tid < 128) {
    const int w = tid >> 6, n = l;
    float acc[25];
#pragma unroll
    for (int s = 0; s < 25; ++s) acc[s] = 0.f;
    const float* qrow = fq + n * FS + w * 64;
    for (int lb = 0; lb < 16; ++lb) {
      float4 qv = *(const float4*)(qrow + 4 * lb);
      const float* qp = (const float*)&qv;
#pragma unroll
      for (int i = 0; i < 4; ++i) {
        const float qs = qp[i];
        const int base = __builtin_amdgcn_readfirstlane((w * 64 + 4 * lb + i) * 25);
#pragma unroll
        for (int s = 0; s < 25; ++s) {
          acc[s] = fmaf(qs, kT[idxg[base + s] * AS + n], acc[s]);
        }
      }
    }
    float* P = Pp + w * 1600;
#pragma unroll
    for (int s = 0; s < 25; ++s) P[s * 64 + n] = acc[s];
  } else if (tid < 256) {
    const int h = tid - 128;
    float acc = 0.f;
    for (int n = 0; n < 64; ++n) {
      acc += fv[n * FS + h];
      outb[n * 128 + h] = fmaf(gamma, acc, xb[n * 128 + h]);
    }
  }
  __syncthreads();

  // ---------------- M + top-25 (value desc, index asc) on wave 0 ----------------
  if (tid < 64) {
    if (tid >= 25 && tid < 32) mte[tid] = 0;
    const float* P0 = Pp;
    const float* P1 = Pp + 1600;
    float mx = -INFINITY, su = 0.f;
#pragma unroll
    for (int s = 0; s < 25; ++s) {
      float vsum = P0[s * 64 + tid] + P1[s * 64 + tid];
      mx = fmaxf(mx, vsum);
      su += vsum;
    }
    float v = mx - su * (1.0f / 128.0f);
    for (int it = 0; it < 25; ++it) {
      float bv2 = v;
      int bi = tid;
#pragma unroll
      for (int off = 32; off > 0; off >>= 1) {
        float ov = __shfl_xor(bv2, off);
        int oi = __shfl_xor(bi, off);
        if (ov > bv2 || (ov == bv2 && oi < bi)) { bv2 = ov; bi = oi; }
      }
      if (tid == 0) mte[it] = bi;
      if (tid == bi) v = -INFINITY;
    }
  }
  __syncthreads();

  // ---------------- dense scores MFMA (waves 0-1) || vT build (rest) ----------------
  float* sc = U + 8704;      // 25*68 (Pp dead)
  float* vT = U;             // 128*68 (kT dead)
  if (tid < 128) {
    const int wsc = tid >> 6;
    const int lr = l & 31;
    const int kg = (l >> 5) * 4;
    const int qr = mte[lr];
    const float scale = 0.08838834764831845f;
    f32x16 acc = (f32x16)0.f;
    for (int ks = 0; ks < 8; ++ks) {
      int kb = ks * 16;
      float4 a0 = *(const float4*)(fq + qr * FS + kb + kg);
      float4 a1 = *(const float4*)(fq + qr * FS + kb + 8 + kg);
      float4 b0 = *(const float4*)(fk + (wsc * 32 + lr) * FS + kb + kg);
      float4 b1 = *(const float4*)(fk + (wsc * 32 + lr) * FS + kb + 8 + kg);
      short8 ah, al2, bh, bl;
      split2(a0, a1, ah, al2);
      split2(b0, b1, bh, bl);
      acc = mm32(ah, bh, acc);
      acc = mm32(ah, bl, acc);
      acc = mm32(al2, bh, acc);
    }
#pragma unroll
    for (int reg = 0; reg < 16; ++reg) {
      int uu = (reg & 3) + 8 * (reg >> 2) + 4 * (l >> 5);
      if (uu < 25) sc[uu * AS + wsc * 32 + lr] = acc[reg] * scale;
    }
  } else {
    for (int i = tid - 128; i < 8192; i += 896) {
      int h2 = i >> 6, n = i & 63;
      vT[h2 * AS + n] = fv[n * FS + h2];
    }
  }
  __syncthreads();

  // ---------------- softmax over n (16 lanes per selected row) ----------------
  if (tid < 400) {
    int u = tid >> 4, g = tid & 15;
    float4* s4 = (float4*)(sc + u * AS);
    float4 v = s4[g];
    float mx = fmaxf(fmaxf(v.x, v.y), fmaxf(v.z, v.w));
    for (int off = 8; off; off >>= 1) mx = fmaxf(mx, __shfl_xor(mx, off));
    float4 e;
    e.x = __expf(v.x - mx); e.y = __expf(v.y - mx);
    e.z = __expf(v.z - mx); e.w = __expf(v.w - mx);
    float su = e.x + e.y + e.z + e.w;
    for (int off = 8; off; off >>= 1) su += __shfl_xor(su, off);
    float inv = 1.0f / su;
    e.x *= inv; e.y *= inv; e.z *= inv; e.w *= inv;
    s4[g] = e;
  }
  __syncthreads();

  // ---------------- upd MFMA: out[mte[u]] = gamma*(attn@v) + x ----------------
  if (tid < 512) {
    const int w8 = tid >> 6;
    const int li = l & 15;
    const int kg4 = (l >> 4) * 4;
#pragma unroll
    for (int i = 0; i < 2; ++i) {
      int t = w8 * 2 + i;
      int ut = t >> 3, ht = t & 7;
      int u = ut * 16 + li;
      f32x4 acc = (f32x4)0.f;
#pragma unroll
      for (int ks = 0; ks < 2; ++ks) {
        int kb = ks * 32;
        float4 a0 = *(const float4*)(sc + u * AS + kb + kg4);
        float4 a1 = *(const float4*)(sc + u * AS + kb + 16 + kg4);
        float4 b0 = *(const float4*)(vT + (ht * 16 + li) * AS + kb + kg4);
        float4 b1 = *(const float4*)(vT + (ht * 16 + li) * AS + kb + 16 + kg4);
        short8 ah, al2, bh, bl;
        split2(a0, a1, ah, al2);
        split2(b0, b1, bh, bl);
        acc = mm16(ah, bh, acc);
        acc = mm16(ah, bl, acc);
        acc = mm16(al2, bh, acc);
      }
      int hcol = ht * 16 + li;
#pragma unroll
      for (int r = 0; r < 4; ++r) {
        int uu = ut * 16 + (l >> 4) * 4 + r;
        if (uu < 25) {
          int row = mte[uu];
          int o = row * 128 + hcol;
          outb[o] = fmaf(gamma, acc[r], xb[o]);
        }
      }
    }
  }
}

extern "C" void kernel_launch(void* const* d_in, const int* in_sizes, int n_in,
                              void* d_out, int out_size, void* d_ws, size_t ws_size,
                              hipStream_t stream) {
  const float* x   = (const float*)d_in[0];
  const float* wq  = (const float*)d_in[1];
  const float* bq  = (const float*)d_in[2];
  const float* wk  = (const float*)d_in[3];
  const float* bk  = (const float*)d_in[4];
  const float* wv  = (const float*)d_in[5];
  const float* bv  = (const float*)d_in[6];
  const float* gw1 = (const float*)d_in[7];
  const float* gb1 = (const float*)d_in[8];
  const float* gw2 = (const float*)d_in[9];
  const float* gb2 = (const float*)d_in[10];
  const float* gm  = (const float*)d_in[11];
  const int* idx   = (const int*)d_in[12];
  float* out = (float*)d_out;
  int B = in_sizes[0] / (64 * 128);
  hipLaunchKernelGGL(gcn_ssa_kernel, dim3(B), dim3(T), 0, stream,
                     x, wq, bq, wk, bk, wv, bv, gw1, gb1, gw2, gb2, gm, idx, out);
}